// Round 6
// baseline (407.790 us; speedup 1.0000x reference)
//
#include <hip/hip_runtime.h>
#include <hip/hip_bf16.h>

#define NTOK 2304
#define CCH  256
#define BB   8
#define NSPL 2

typedef __attribute__((ext_vector_type(4))) float f32x4;
typedef __attribute__((ext_vector_type(8))) short s16x8;
typedef __attribute__((ext_vector_type(8))) _Float16 h16x8;
typedef unsigned short u16;
typedef unsigned char u8;

__device__ __forceinline__ u16 f2bf(float x){
  union{float f; unsigned u;} v; v.f = x;
  unsigned r = v.u + 0x7fffu + ((v.u>>16)&1u);
  return (u16)(r>>16);
}
__device__ __forceinline__ float bf2f(u16 h){
  union{float f; unsigned u;} v; v.u = ((unsigned)h)<<16; return v.f;
}

// ---- fp8 codec: HW OCP e4m3fn if available, else manual 2^±120 scheme ----
#if __has_builtin(__builtin_amdgcn_cvt_f32_fp8) && __has_builtin(__builtin_amdgcn_cvt_pk_fp8_f32)
#define HWFP8 1
#else
#define HWFP8 0
#endif

__device__ __forceinline__ u8 enc8(float z){
  union{float f; unsigned u;} a; a.f = fabsf(z) * 0x1p-120f;
  unsigned u = a.u + 0x7FFFFu + ((a.u>>20)&1u);
  unsigned b = (u>>20)&0x7Fu;
  if (b > 0x7Eu) b = 0x7Eu;
  return (u8)(b | (z<0.f ? 0x80u : 0u));
}
__device__ __forceinline__ float dec8(unsigned b){
  union{unsigned u; float f;} w;
  w.u = ((b&0x80u)<<24) | ((b&0x7Fu)<<20);
  return w.f * 0x1p120f;
}

#if HWFP8
// builtin needs a LITERAL byte-select; switch folds after unroll+constprop
__device__ __forceinline__ float DEC8(unsigned w, int e){
  switch(e & 3){
    case 0:  return __builtin_amdgcn_cvt_f32_fp8((int)w, 0);
    case 1:  return __builtin_amdgcn_cvt_f32_fp8((int)w, 1);
    case 2:  return __builtin_amdgcn_cvt_f32_fp8((int)w, 2);
    default: return __builtin_amdgcn_cvt_f32_fp8((int)w, 3);
  }
}
__device__ __forceinline__ unsigned pack4(float z0,float z1,float z2,float z3){
  int v = __builtin_amdgcn_cvt_pk_fp8_f32(z0, z1, 0, false);
  v = __builtin_amdgcn_cvt_pk_fp8_f32(z2, z3, v, true);
  return (unsigned)v;
}
#else
__device__ __forceinline__ float DEC8(unsigned w, int e){
  return dec8((w>>(8*(e&3)))&0xFFu);
}
__device__ __forceinline__ unsigned pack4(float z0,float z1,float z2,float z3){
  return (unsigned)enc8(z0) | ((unsigned)enc8(z1)<<8) |
         ((unsigned)enc8(z2)<<16) | ((unsigned)enc8(z3)<<24);
}
#endif

// swizzles: rows of 512B (256 bf16), 128B (64 bf16), 64B (32 bf16)
__device__ __forceinline__ int swz512(int row, int b){ return row*512 + (b ^ ((row&7)<<4)); }
__device__ __forceinline__ int swz128(int row, int b){ return row*128 + (b ^ ((row&7)<<4)); }
__device__ __forceinline__ int swz64 (int row, int b){ return row*64  + (b ^ ((row&3)<<4)); }

// async global->LDS, 16B per lane; LDS dest is wave-uniform base + lane*16
__device__ __forceinline__ void gl_lds16(const void* g, void* l){
  __builtin_amdgcn_global_load_lds(
      (const __attribute__((address_space(1))) unsigned int*)g,
      (__attribute__((address_space(3))) unsigned int*)l, 16, 0, 0);
}

struct CanonArgs {
  const void* src[31];
  int n[31];
  int off[31];
};

// ---------------- dtype detect + canonicalize to f32 ----------------
__global__ void k_detect(const u16* probe, int* flag){
  if (threadIdx.x==0){
    int cnt=0;
    for (int i=0;i<16;++i){
      unsigned e = (probe[2*i]>>7)&0xFFu;
      if (e>=100u && e<=140u) ++cnt;
    }
    *flag = (cnt>=14)?1:0;   // 1 => inputs are bf16
  }
}

__global__ __launch_bounds__(256) void k_canon(CanonArgs a, float* dst, const int* flag, int nt){
  int t = blockIdx.y;
  if (t>=nt) return;
  int n = a.n[t];
  const void* s = a.src[t];
  float* d = dst + a.off[t];
  bool isbf = (*flag)!=0;
  int n4 = n >> 2;
  for (int i = blockIdx.x*256+threadIdx.x; i < n4; i += gridDim.x*256){
    if (isbf){
      ushort4 v = ((const ushort4*)s)[i];
      float4 o; o.x=bf2f(v.x); o.y=bf2f(v.y); o.z=bf2f(v.z); o.w=bf2f(v.w);
      ((float4*)d)[i] = o;
    } else {
      ((float4*)d)[i] = ((const float4*)s)[i];
    }
  }
  int base = n4<<2;
  int rem = n - base;
  int i = blockIdx.x*256+threadIdx.x;
  if (i < rem)
    d[base+i] = isbf ? bf2f(((const u16*)s)[base+i]) : ((const float*)s)[base+i];
}

// ---------------- zero f32 buffer ----------------
__global__ __launch_bounds__(256) void k_zero(float* p, int n4){
  int i = blockIdx.x*256+threadIdx.x;
  if (i < n4) ((float4*)p)[i] = (float4){0.f,0.f,0.f,0.f};
}

// ---------------- text path: txt_emb, txt_n, attn_vec ----------------
__global__ __launch_bounds__(256) void k_txt(const float* txt, const float* tpw, const float* tpb,
    const float* wv, const float* bv, const float* wo, const float* bo, float* TXTN, float* AVEC){
  int b=blockIdx.x, t=threadIdx.x;
  __shared__ float sT[512];
  __shared__ float sE[256];
  __shared__ float sV[256];
  __shared__ float red[4];
  sT[t]      = txt[b*512+t];
  sT[t+256]  = txt[b*512+256+t];
  __syncthreads();
  float acc = tpb[t];
  const float* wr = tpw + (size_t)t*512;
  for (int k=0;k<512;++k) acc = fmaf(sT[k], wr[k], acc);
  sE[t] = acc;
  float ss = acc*acc;
  for (int d=1; d<64; d<<=1) ss += __shfl_xor(ss, d);
  if ((t&63)==0) red[t>>6] = ss;
  __syncthreads();
  float nrm = sqrtf(red[0]+red[1]+red[2]+red[3]);
  TXTN[b*256+t] = acc / fmaxf(nrm, 1e-12f);
  float av = bv[t];
  const float* wvr = wv + (size_t)t*256;
  for (int k=0;k<256;++k) av = fmaf(sE[k], wvr[k], av);
  sV[t] = av;
  __syncthreads();
  float ao = bo[t];
  const float* wor = wo + (size_t)t*256;
  for (int k=0;k<256;++k) ao = fmaf(sV[k], wor[k], ao);
  AVEC[b*256+t] = ao;
}

// -------- fused transpose + residual + layernorm + l2norm + cos --------
__global__ __launch_bounds__(256) void k_lnfuse(const float* img, const float* AVEC, const float* lng,
    const float* lnb, const float* TXTN, u16* SF, u16* SN, float* COS){
  int b=blockIdx.y, n0=blockIdx.x*32, t=threadIdx.x;
  __shared__ float xt[32][256];
  float av = AVEC[b*256+t];
  const float* ip = img + ((size_t)b*256 + t)*NTOK + n0;
  #pragma unroll
  for (int j4=0;j4<8;++j4){
    float4 v = *(const float4*)(ip + j4*4);
    xt[j4*4+0][t]=v.x+av; xt[j4*4+1][t]=v.y+av; xt[j4*4+2][t]=v.z+av; xt[j4*4+3][t]=v.w+av;
  }
  int wv_=t>>6, l=t&63;
  float lg[4], lb[4], tn[4];
  #pragma unroll
  for (int k=0;k<4;++k){ lg[k]=lng[l+64*k]; lb[k]=lnb[l+64*k]; tn[k]=TXTN[b*256+l+64*k]; }
  __syncthreads();
  for (int rr=0; rr<8; ++rr){
    int j = wv_*8+rr; int n = n0+j;
    float x[4]; float s=0.f, ss=0.f;
    #pragma unroll
    for (int k=0;k<4;++k){ float v=xt[j][l+64*k]; x[k]=v; s+=v; ss=fmaf(v,v,ss); }
    for (int d=1; d<64; d<<=1){ s += __shfl_xor(s,d); ss += __shfl_xor(ss,d); }
    float mu = s*(1.f/256.f);
    float var = ss*(1.f/256.f) - mu*mu;
    float rstd = rsqrtf(fmaxf(var,0.f)+1e-5f);
    float y[4]; float sy=0.f;
    #pragma unroll
    for (int k=0;k<4;++k){ y[k] = fmaf((x[k]-mu)*rstd, lg[k], lb[k]); sy = fmaf(y[k],y[k],sy); }
    for (int d=1; d<64; d<<=1) sy += __shfl_xor(sy,d);
    float rn = 1.f/fmaxf(sqrtf(sy),1e-12f);
    float cp = 0.f;
    size_t base = ((size_t)b*NTOK + n)*CCH;
    #pragma unroll
    for (int k=0;k<4;++k){
      float sv = y[k]*rn;
      SF[base + l+64*k] = f2bf(y[k]);
      SN[base + l+64*k] = f2bf(sv);
      cp = fmaf(sv, tn[k], cp);
    }
    for (int d=1; d<64; d<<=1) cp += __shfl_xor(cp,d);
    if (l==0) COS[b*NTOK+n] = cp;
  }
}

// -------- per-b reductions for p and q --------
__global__ __launch_bounds__(256) void k_pqred(const float* COS, const float* den, const float* tmpp, float* PQS){
  int b=blockIdx.x, t=threadIdx.x;
  __shared__ float red[256];
  float temp = fmaxf(tmpp[0], 0.01f);
  float mx = -1e30f;
  for (int n=t; n<NTOK; n+=256) mx = fmaxf(mx, COS[b*NTOK+n]);
  red[t]=mx; __syncthreads();
  for (int o=128;o>0;o>>=1){ if (t<o) red[t]=fmaxf(red[t],red[t+o]); __syncthreads(); }
  float maxc = red[0]; __syncthreads();
  float sp=0.f, st=0.f;
  for (int n=t; n<NTOK; n+=256){
    float cv = COS[b*NTOK+n];
    sp += __expf((cv-maxc)/temp)*((cv>0.f)?1.f:0.f)+1e-8f;
    float dv = den[b*NTOK+n];
    st += fmaxf(dv,0.f)+1e-6f;
  }
  red[t]=sp; __syncthreads();
  for (int o=128;o>0;o>>=1){ if (t<o) red[t]+=red[t+o]; __syncthreads(); }
  sp = red[0]; __syncthreads();
  red[t]=st; __syncthreads();
  for (int o=128;o>0;o>>=1){ if (t<o) red[t]+=red[t+o]; __syncthreads(); }
  if (t==0){ PQS[b*4]=maxc; PQS[b*4+1]=sp; PQS[b*4+2]=red[0]; }
}

// Also builds PJ[n] = (n/48)*95 + n%48 (u16) and the 95x95 spatial-cost table
// SPT[(dh+47)*95 + (dw+47)] = spw20 * sqrt(dh^2+dw^2)/47  (f32, exact sqrt)
__global__ __launch_bounds__(256) void k_pqelem(const float* COS, const float* den, const float* tmpp,
    const float* swp, const float* PQS, float* LOGP, float* LOGQ, float* GV, u16* PJ, float* SPT){
  int idx = blockIdx.x*256+threadIdx.x;
  float temp = fmaxf(tmpp[0], 0.01f);
  if (idx < BB*NTOK){
    int b = idx / NTOK;
    float maxc = PQS[b*4], sp = PQS[b*4+1], st = PQS[b*4+2];
    float cv = COS[idx];
    float pu = __expf((cv-maxc)/temp)*((cv>0.f)?1.f:0.f)+1e-8f;
    LOGP[idx] = logf(pu/sp + 1e-12f);
    float dv = den[idx];
    LOGQ[idx] = logf((fmaxf(dv,0.f)+1e-6f)/st + 1e-12f);
    GV[idx] = 0.f;
  }
  if (idx < NTOK){
    int h = idx/48, w = idx - h*48;
    PJ[idx] = (u16)(h*95 + w);
  }
  if (idx < 9025){
    int dh = idx/95 - 47, dw = idx - (idx/95)*95 - 47;
    float spw = swp[0]*(20.0f/1.41421356f);
    float dy = (float)dh*(1.f/47.f), dx = (float)dw*(1.f/47.f);
    SPT[idx] = spw*sqrtf(fmaf(dy,dy,dx*dx));
  }
}

// -------- weight repack for conv heads -> chunk-major [36 kc][256 o][64 c] bf16 --------
// kc = tap*4 + cquad; o = head*128+oc; per-chunk 32KB tile is CONTIGUOUS for gl_lds staging.
__global__ __launch_bounds__(256) void k_packw(const float* h1w, const float* v1w, u16* W2P){
  int idx = blockIdx.x*256+threadIdx.x; // < 589824 = 36*16384
  int kc = idx >> 14;
  int rem = idx & 16383;
  int o = rem >> 6;
  int cl = rem & 63;
  int tap = kc >> 2;
  int c = ((kc&3)<<6) + cl;
  int head = o >> 7, oc = o & 127;
  const float* src = head ? v1w : h1w;
  W2P[idx] = f2bf(src[(oc*256 + c)*9 + tap]);
}

// -------- SF transpose: SFT[b][c][nP] = SF[b][true(nP)][c], n permuted within 64-blocks --------
// stored p <-> true t within 64-block: t = (p&3)*16 + (p>>2)   (p = (t&15)*4 + (t>>4))
__global__ __launch_bounds__(256) void k_trans(const u16* SF, u16* SFT){
  int n0 = blockIdx.x*64, c0 = blockIdx.y*64, b = blockIdx.z;
  __shared__ u16 tl[64][68];
  int t = threadIdx.x;
  int nl = t>>3, c8 = (t&7)*8;
  #pragma unroll
  for (int p=0;p<2;++p){
    int n = nl + p*32;
    s16x8 v = *(const s16x8*)(SF + ((size_t)(b*NTOK + n0+n)*CCH + c0 + c8));
    #pragma unroll
    for (int e=0;e<8;++e) tl[c8+e][n] = (u16)v[e];
  }
  __syncthreads();
  int cl = t>>3, n8 = (t&7)*8;
  #pragma unroll
  for (int p=0;p<2;++p){
    int c = cl + p*32;
    union{ s16x8 v; u16 us[8]; } pk;
    #pragma unroll
    for (int e=0;e<8;++e){ int s = n8+e; pk.us[e] = tl[c][((s&3)<<4) | (s>>2)]; }
    *(s16x8*)(SFT + ((size_t)(b*CCH + c0+c)*NTOK + n0 + n8)) = pk.v;
  }
}

// -------- cost build (64x256 tiles), fp8 Z stored col-PERMUTED per 64-block --------
// Pipelined: MFMA -> barrier -> STAGE(js+1) -> epilogue (its SPT loads drain the
// staging via in-order vmcnt retirement) -> raw barrier (no vmcnt-0 drain).
// Spatial term via precomputed SPT table (kills per-element sqrt).
__global__ __launch_bounds__(256, 5) void k_cost(const u16* SN, const u16* PJ, const float* SPT,
    u8* Z, float* PZ, int b_base){
  int zb = blockIdx.z, b = b_base + zb;
  int i0 = blockIdx.x*64, by = blockIdx.y, j0b = by*256;
  const u16* SNb = SN + (size_t)b*NTOK*CCH;
  u8* Zb = Z + (size_t)zb*NTOK*NTOK;
  __shared__ __align__(16) char Bs[64*512];
  int tid=threadIdx.x, w=tid>>6, l=tid&63, g4=l>>4, lc=l&15;
  const u16* Arow = SNb + (size_t)(i0 + w*16 + lc)*CCH + g4*8;
  s16x8 af[8];
  #pragma unroll
  for (int ks=0; ks<8; ++ks) af[ks] = *(const s16x8*)(Arow + ks*32);
  int mrow = w*16 + g4*4;
  int ipi[4];
  #pragma unroll
  for (int r=0;r<4;++r) ipi[r] = (int)PJ[i0+mrow+r] + 4512;   // +47*95+47
  float Srow[4] = {0.f,0.f,0.f,0.f};
  auto STAGE = [&](int js){
    int j0 = j0b + js*64;
    #pragma unroll
    for (int u=0; u<8; ++u){
      int row = u*8 + w*2 + (l>>5);
      int src = ((l&31)*16) ^ ((row&7)<<4);   // pre-swizzled source, linear LDS dest
      gl_lds16((const char*)(SNb + (size_t)(j0+row)*CCH) + src, Bs + u*4096 + w*1024);
    }
  };
  STAGE(0);
  __syncthreads();                      // initial drain, once
  for (int js=0; js<4; ++js){
    int j0 = j0b + js*64;
    f32x4 acc[4];
    #pragma unroll
    for (int cf=0;cf<4;++cf) acc[cf] = (f32x4){0.f,0.f,0.f,0.f};
    #pragma unroll
    for (int ks=0; ks<8; ++ks){
      int kb = ks*64 + g4*16;
      #pragma unroll
      for (int cf=0; cf<4; ++cf){
        s16x8 bb = *(const s16x8*)(Bs + swz512(cf*16+lc, kb));
        acc[cf] = __builtin_amdgcn_mfma_f32_16x16x32_bf16(af[ks], bb, acc[cf], 0,0,0);
      }
    }
    __builtin_amdgcn_sched_barrier(0);
    __builtin_amdgcn_s_barrier();       // all waves done reading Bs (ds_reads retired via MFMA operand waits)
    __builtin_amdgcn_sched_barrier(0);
    if (js < 3) STAGE(js+1);            // stays in flight under the epilogue
    __builtin_amdgcn_sched_barrier(0);
    // ---- epilogue: spatial table + fp8 pack + store + first-pass row sum ----
    float zf[4][4];
    #pragma unroll
    for (int cf=0; cf<4; ++cf){
      int j = j0 + cf*16 + lc;          // TRUE column
      int pjj = (int)PJ[j];
      #pragma unroll
      for (int r=0;r<4;++r){
        float sp = SPT[ipi[r] - pjj];
        zf[cf][r] = (acc[cf][r]-1.0f)*20.0f - sp;
      }
    }
    size_t zrow = (size_t)(i0+mrow)*NTOK + j0 + lc*4;   // stored (permuted) position
    #pragma unroll
    for (int r=0;r<4;++r){
      unsigned pw = pack4(zf[0][r], zf[1][r], zf[2][r], zf[3][r]);
      Srow[r] += __expf(DEC8(pw,0)) + __expf(DEC8(pw,1))
               + __expf(DEC8(pw,2)) + __expf(DEC8(pw,3));
      *(unsigned*)(Zb + zrow + (size_t)r*NTOK) = pw;
    }
    __builtin_amdgcn_sched_barrier(0);
    __builtin_amdgcn_s_barrier();       // staging drained by epilogue's load waits; no vmcnt(0)
    __builtin_amdgcn_sched_barrier(0);
  }
  #pragma unroll
  for (int r=0;r<4;++r){
    float s = Srow[r];
    s += __shfl_xor(s,1); s += __shfl_xor(s,2); s += __shfl_xor(s,4); s += __shfl_xor(s,8);
    if (lc==0) PZ[(size_t)(zb*NTOK + i0 + mrow + r)*9 + by] = s;
  }
}

// -------- combine 9 per-block partials -> first f-pass output (max = 0) --------
__global__ __launch_bounds__(256) void k_sinkred(const float* PZ, const float* LOGP, float* FV,
    int b_base, int zcnt){
  int idx = blockIdx.x*256 + threadIdx.x;
  if (idx >= zcnt*NTOK) return;
  int zb = idx / NTOK, row = idx - zb*NTOK, b = b_base + zb;
  const float* p = PZ + (size_t)idx*9;
  float s = 0.f;
  #pragma unroll
  for (int k=0;k<9;++k) s += p[k];
  FV[b*NTOK+row] = 0.05f*(LOGP[b*NTOK+row] - logf(s));
}

// -------- Sinkhorn half-iteration with FIXED shift C = max_j(add_j*20), permuted fp8 Z --------
// 32 rows/block, 8 lanes/row; C folded into fs once.
__global__ __launch_bounds__(256) void k_sinkZ(const u8* Z, const float* addv,
    const float* basev, float* outv, int b_base){
  int zb = blockIdx.y, b = b_base + zb, i0 = blockIdx.x*32;
  __shared__ float fs[NTOK];   // filled in STORED (permuted) order
  __shared__ float wm[4];
  int t = threadIdx.x;
  for (int j=t; j<NTOK; j+=256){
    int p = j & 63, tt = ((p&3)<<4) | (p>>2);
    fs[j] = addv[b*NTOK + (j & ~63) + tt]*20.f;
  }
  __syncthreads();
  float m = -1e30f;
  for (int j=t; j<NTOK; j+=256) m = fmaxf(m, fs[j]);
  #pragma unroll
  for (int d=1; d<64; d<<=1) m = fmaxf(m, __shfl_xor(m, d));
  if ((t&63)==0) wm[t>>6] = m;
  __syncthreads();
  float C = fmaxf(fmaxf(wm[0],wm[1]), fmaxf(wm[2],wm[3]));
  __syncthreads();
  for (int j=t; j<NTOK; j+=256) fs[j] -= C;
  __syncthreads();
  int rl = t>>3, q = t&7;
  int row = i0 + rl;
  const u8* zr = Z + ((size_t)zb*NTOK + row)*NTOK;
  float S = 0.f;
  for (int c0 = q*32; c0 < NTOK; c0 += 256){
    uint4 zA = *(const uint4*)(zr + c0);
    uint4 zB = *(const uint4*)(zr + c0 + 16);
    unsigned wd[8] = {zA.x,zA.y,zA.z,zA.w, zB.x,zB.y,zB.z,zB.w};
    float s32 = 0.f;
    #pragma unroll
    for (int k=0;k<8;++k)
      #pragma unroll
      for (int e=0;e<4;++e)
        s32 += __expf(fs[c0 + k*4 + e] + DEC8(wd[k], e));
    S += s32;
  }
  #pragma unroll
  for (int d=1; d<8; d<<=1) S += __shfl_xor(S, d);
  if (q==0)
    outv[b*NTOK+row] = 0.05f*(basev[b*NTOK+row] - (C + logf(S)));
}

// -------- fused[m,c] += sum_n T[n,m]*SF[n,c] over this split's n-range --------
__global__ __launch_bounds__(256, 3) void k_applyT(const u8* Z, const u16* SFT, const float* FVv,
    const float* GVv, float* FUF, int b_base){
  int zb = blockIdx.z, b = b_base + zb, m0 = blockIdx.x*64;
  int sp = blockIdx.y;
  int nbeg = sp*(NTOK/NSPL), nend = nbeg + (NTOK/NSPL);
  __shared__ __align__(16) char WtL[64*128];   // [m][64 nP] bf16, swz128
  __shared__ __align__(16) char BL[256*128];   // [c][64 nP] bf16, swz128 (via pre-swz source)
  __shared__ float gs[64];
  __shared__ float sfv[NTOK/NSPL];             // f*20 in STORED (permuted) order
  int tid=threadIdx.x, w=tid>>6, l=tid&63, g4=l>>4, lc=l&15;
  if (tid<64) gs[tid] = GVv[b*NTOK+m0+tid]*20.f;
  const float* Fv = FVv + b*NTOK;
  for (int j=tid; j<NTOK/NSPL; j+=256){
    int jj = nbeg + j;
    int p = jj & 63, tt = ((p&3)<<4) | (p>>2);
    sfv[j] = Fv[(jj & ~63) + tt]*20.f;
  }
  const u8* Zb = Z + ((size_t)zb*NTOK + m0)*NTOK;
  const u16* SFTb = SFT + (size_t)b*CCH*NTOK;
  f32x4 acc[4][4];
  #pragma unroll
  for (int mf=0;mf<4;++mf)
    #pragma unroll
    for (int cf=0;cf<4;++cf) acc[mf][cf] = (f32x4){0.f,0.f,0.f,0.f};
  int zm = tid>>2, zq = (tid&3)*16;
  int lrow = l>>3;
  int lsrc = ((l&7)*16) ^ (lrow<<4);
  uint4 zwc = *(const uint4*)(Zb + (size_t)zm*NTOK + nbeg + zq);
  for (int n0=nbeg; n0<nend; n0+=64){
    __syncthreads();
    int nn = (n0+64 < nend) ? n0+64 : nbeg;
    uint4 zwn = *(const uint4*)(Zb + (size_t)zm*NTOK + nn + zq);
    #pragma unroll
    for (int u=0; u<8; ++u){
      int row = w*64 + u*8 + lrow;
      gl_lds16((const char*)(SFTb + (size_t)row*NTOK) + n0*2 + lsrc,
               BL + (w*64 + u*8)*128);
    }
    {
      float g20 = gs[zm];
      unsigned wd[4] = {zwc.x, zwc.y, zwc.z, zwc.w};
      union{ s16x8 v; u16 us[8]; } w0, w1;
      int sbase = n0 - nbeg + zq;
      #pragma unroll
      for (int col=0; col<16; ++col){
        float val = __expf(sfv[sbase+col] + g20 + DEC8(wd[col>>2], col&3));
        if (col < 8) w0.us[col] = f2bf(val); else w1.us[col-8] = f2bf(val);
      }
      *(s16x8*)(WtL + swz128(zm, zq*2)) = w0.v;
      *(s16x8*)(WtL + swz128(zm, zq*2+16)) = w1.v;
    }
    __syncthreads();
    #pragma unroll
    for (int kk=0; kk<2; ++kk){
      s16x8 a[4];
      #pragma unroll
      for (int mf=0;mf<4;++mf) a[mf] = *(const s16x8*)(WtL + swz128(mf*16+lc, kk*64 + g4*16));
      #pragma unroll
      for (int cf=0; cf<4; ++cf){
        s16x8 bb = *(const s16x8*)(BL + swz128(w*64+cf*16+lc, kk*64 + g4*16));
        #pragma unroll
        for (int mf=0; mf<4; ++mf)
          acc[mf][cf] = __builtin_amdgcn_mfma_f32_16x16x32_bf16(a[mf], bb, acc[mf][cf], 0,0,0);
      }
    }
    zwc = zwn;
  }
  float* FUb = FUF + (size_t)b*NTOK*CCH;
  #pragma unroll
  for (int mf=0; mf<4; ++mf)
    #pragma unroll
    for (int cf=0; cf<4; ++cf)
      #pragma unroll
      for (int r=0;r<4;++r){
        int m = m0 + mf*16 + g4*4 + r;
        int c = w*64 + cf*16 + lc;
        atomicAdd(&FUb[(size_t)m*CCH + c], acc[mf][cf][r]);
      }
}

// -------- out_feat = img + op_w @ fused + op_b (f32 out); also [b][n][c] bf16 copy --------
__global__ __launch_bounds__(256) void k_opgemm(const float* FUF, const float* opw, const float* opb,
    const float* img, float* dout, u16* OFN){
  int b=blockIdx.y, n0=blockIdx.x*64;
  __shared__ __align__(16) char Am[64*512];
  __shared__ __align__(16) char Bw[256*64];
  int tid=threadIdx.x, w=tid>>6, l=tid&63, g4=l>>4, lc=l&15;
  const float* FUb = FUF + (size_t)b*NTOK*CCH;
  for (int ch=tid; ch<64*32; ch+=256){
    int r=ch>>5, c8=(ch&31)*8;
    const float* fp = FUb + (size_t)(n0+r)*CCH + c8;
    float4 v0 = *(const float4*)fp;
    float4 v1 = *(const float4*)(fp+4);
    union { s16x8 v; u16 us[8]; } pk;
    pk.us[0]=f2bf(v0.x); pk.us[1]=f2bf(v0.y); pk.us[2]=f2bf(v0.z); pk.us[3]=f2bf(v0.w);
    pk.us[4]=f2bf(v1.x); pk.us[5]=f2bf(v1.y); pk.us[6]=f2bf(v1.z); pk.us[7]=f2bf(v1.w);
    *(s16x8*)(Am + swz512(r, c8*2)) = pk.v;
  }
  f32x4 acc[4][4];
  #pragma unroll
  for (int mf=0;mf<4;++mf)
    #pragma unroll
    for (int cf=0;cf<4;++cf) acc[mf][cf] = (f32x4){0.f,0.f,0.f,0.f};
  for (int ks=0; ks<8; ++ks){
    __syncthreads();
    {
      int o = tid;
      const float* wr = opw + (size_t)o*CCH + ks*32;
      #pragma unroll
      for (int u=0; u<4; ++u){
        float4 v0 = *(const float4*)(wr + u*8);
        float4 v1 = *(const float4*)(wr + u*8 + 4);
        union { s16x8 v; u16 us[8]; } pk;
        pk.us[0]=f2bf(v0.x); pk.us[1]=f2bf(v0.y); pk.us[2]=f2bf(v0.z); pk.us[3]=f2bf(v0.w);
        pk.us[4]=f2bf(v1.x); pk.us[5]=f2bf(v1.y); pk.us[6]=f2bf(v1.z); pk.us[7]=f2bf(v1.w);
        *(s16x8*)(Bw + swz64(o, u*16)) = pk.v;
      }
    }
    __syncthreads();
    #pragma unroll
    for (int mf=0; mf<4; ++mf){
      s16x8 a = *(const s16x8*)(Am + swz512(mf*16+lc, (ks*32+g4*8)*2));
      #pragma unroll
      for (int cf=0; cf<4; ++cf){
        int o = w*64+cf*16+lc;
        s16x8 bb = *(const s16x8*)(Bw + swz64(o, g4*16));
        acc[mf][cf] = __builtin_amdgcn_mfma_f32_16x16x32_bf16(a, bb, acc[mf][cf], 0,0,0);
      }
    }
  }
  #pragma unroll
  for (int mf=0; mf<4; ++mf){
    int nl = mf*16 + g4*4; int n = n0+nl;
    #pragma unroll
    for (int cf=0; cf<4; ++cf){
      int o = w*64+cf*16+lc;
      float ob = opb[o];
      const float* ip = img + ((size_t)b*CCH + o)*NTOK + n;
      float4 im = *(const float4*)ip;
      float o0 = acc[mf][cf][0]+ob+im.x;
      float o1 = acc[mf][cf][1]+ob+im.y;
      float o2 = acc[mf][cf][2]+ob+im.z;
      float o3 = acc[mf][cf][3]+ob+im.w;
      float4 st; st.x=o0; st.y=o1; st.z=o2; st.w=o3;
      *(float4*)(dout + ((size_t)b*CCH+o)*NTOK + n) = st;
      u16* ofp = OFN + ((size_t)b*NTOK + n)*CCH + o;
      ofp[0]=f2bf(o0); ofp[CCH]=f2bf(o1); ofp[2*CCH]=f2bf(o2); ofp[3*CCH]=f2bf(o3);
    }
  }
}

// -------- fused conv3x3 heads as LDS-staged implicit GEMM, pipelined --------
__global__ __launch_bounds__(256, 2) void k_conv2(const u16* OFN, const u16* W2P,
    const float* h1b, const float* v1b, u16* H1, u16* H2){
  int b = blockIdx.y, n0 = blockIdx.x*64;
  __shared__ __align__(16) char As[64*128];        // [row][64 K] bf16 swz128
  __shared__ __align__(16) char Ws[2][256*128];    // [o][64 K] bf16 swz128, double buffer
  int tid=threadIdx.x, w=tid>>6, l=tid&63, g4=l>>4, lc=l&15;
  int ar = tid>>2, aseg = (tid&3)*16;
  int arow = n0 + ar;
  int hr = arow/48, wc = arow - hr*48;
  const u16* Ob = OFN + (size_t)b*NTOK*CCH;
  int wrow = tid>>3;                                // 0..31 (row in 32-row group)
  int wsrc = ((tid&7)*16) ^ ((wrow&7)<<4);          // pre-swizzled byte offset in 128B row
  const char* Wbase = (const char*)W2P;             // [36][256][64] bf16, 32768 B/chunk
  f32x4 acc[4][4];
  #pragma unroll
  for (int mf=0;mf<4;++mf)
    #pragma unroll
    for (int of=0;of<4;++of) acc[mf][of] = (f32x4){0.f,0.f,0.f,0.f};
  auto STAGEW = [&](int kc, int buf){
    const char* src = Wbase + (size_t)kc*32768;
    #pragma unroll
    for (int u=0; u<8; ++u)
      gl_lds16(src + (size_t)(u*32 + wrow)*128 + wsrc, Ws[buf] + u*4096 + w*1024);
  };
  auto LOADA = [&](int kc, s16x8& ra0, s16x8& ra1){
    int tap = kc>>2, cq = (kc&3)*64;
    int kh = tap/3;
    int dh = kh-1, dw = (tap-kh*3)-1;
    bool val = ((unsigned)(hr+dh) < 48u) && ((unsigned)(wc+dw) < 48u);
    ra0 = (s16x8){0,0,0,0,0,0,0,0}; ra1 = ra0;
    if (val){
      const u16* ap = Ob + (size_t)(arow + dh*48 + dw)*CCH + cq + aseg;
      ra0 = *(const s16x8*)ap;
      ra1 = *(const s16x8*)(ap+8);
    }
  };
  s16x8 a0, a1, na0, na1;
  STAGEW(0, 0);
  LOADA(0, a0, a1);
  for (int kc=0; kc<36; ++kc){
    int cur = kc & 1;
    __builtin_amdgcn_s_barrier();      // all waves done reading As & Ws[cur^1] (prev MFMA)
    __builtin_amdgcn_sched_barrier(0);
    if (kc+1 < 36){                     // issue next chunk staging; stays in flight past barrier 2
      STAGEW(kc+1, cur^1);
      LOADA(kc+1, na0, na1);
    }
    // A ds_write: compiler inserts COUNTED vmcnt wait for a0/a1 (drains this chunk's
    // staging, leaves next chunk's loads in flight)
    *(s16x8*)(As + swz128(ar, aseg*2))    = a0;
    *(s16x8*)(As + swz128(ar, aseg*2+16)) = a1;
    asm volatile("s_waitcnt lgkmcnt(0)" ::: "memory");   // my ds_writes landed
    __builtin_amdgcn_s_barrier();      // all writes visible; NO vmcnt(0) drain
    __builtin_amdgcn_sched_barrier(0);
    #pragma unroll
    for (int ks=0; ks<2; ++ks){
      s16x8 af[4];
      #pragma unroll
      for (int mf=0;mf<4;++mf) af[mf] = *(const s16x8*)(As + swz128(mf*16+lc, ks*64 + g4*16));
      #pragma unroll
      for (int of=0; of<4; ++of){
        s16x8 bf = *(const s16x8*)(Ws[cur] + swz128(w*64+of*16+lc, ks*64 + g4*16));
        #pragma unroll
        for (int mf=0; mf<4; ++mf)
          acc[mf][of] = __builtin_amdgcn_mfma_f32_16x16x32_bf16(af[mf], bf, acc[mf][of], 0,0,0);
      }
    }
    a0 = na0; a1 = na1;
  }
  #pragma unroll
  for (int of=0; of<4; ++of){
    int o = w*64 + of*16 + lc;
    int head = o>>7, oc = o&127;
    float bias = (head? v1b : h1b)[oc];
    u16* Hh = head? H2 : H1;
    #pragma unroll
    for (int mf=0; mf<4; ++mf){
      #pragma unroll
      for (int r=0;r<4;++r){
        int n = n0 + mf*16 + g4*4 + r;
        Hh[((size_t)b*NTOK+n)*128 + oc] = f2bf(acc[mf][of][r] + bias);
      }
    }
  }
}

// -------- BN batch stats (two-stage, deterministic) --------
__global__ __launch_bounds__(128) void k_stats(const u16* H1, const u16* H2, float* PART){
  int head=blockIdx.y, blk=blockIdx.x, t=threadIdx.x;
  const u16* Hh = head? H2:H1;
  float s=0.f, ss=0.f;
  size_t r0 = (size_t)blk*288;
  for (int r=0;r<288;++r){
    float v = bf2f(Hh[(r0+r)*128 + t]);
    s += v; ss = fmaf(v,v,ss);
  }
  PART[((head*64+blk)*128+t)*2]   = s;
  PART[((head*64+blk)*128+t)*2+1] = ss;
}

__global__ __launch_bounds__(128) void k_statr(const float* PART, const float* hbg, const float* hbb,
    const float* vbg, const float* vbb, float* BNS){
  int head=blockIdx.x, t=threadIdx.x;
  float s=0.f, ss=0.f;
  for (int blk=0;blk<64;++blk){
    s  += PART[((head*64+blk)*128+t)*2];
    ss += PART[((head*64+blk)*128+t)*2+1];
  }
  float mean = s*(1.f/18432.f);
  float var = ss*(1.f/18432.f) - mean*mean;
  var = fmaxf(var, 0.f);
  const float* g  = head? vbg:hbg;
  const float* be = head? vbb:hbb;
  float sc = g[t]/sqrtf(var+1e-5f);
  BNS[(head*128+t)*2]   = sc;
  BNS[(head*128+t)*2+1] = be[t] - mean*sc;
}

// -------- BN-normalize + relu + conv1x1(128->2), f32 out --------
__global__ __launch_bounds__(128) void k_fin(const u16* H1, const u16* H2, const float* BNS,
    const float* h2w, const float* h2b, const float* v2w, const float* v2b, float* dout){
  int head = blockIdx.z, b = blockIdx.y, n0 = blockIdx.x*128, t=threadIdx.x;
  const u16* Hh = head? H2:H1;
  const float* w2 = head? v2w:h2w;
  const float* b2 = head? v2b:h2b;
  __shared__ u16 tile[128][130];
  __shared__ float sc[128], bi[128], wa[128], wb[128];
  sc[t]=BNS[(head*128+t)*2]; bi[t]=BNS[(head*128+t)*2+1];
  wa[t]=w2[t]; wb[t]=w2[128+t];
  for (int r=0;r<128;++r) tile[r][t] = Hh[((size_t)b*NTOK+n0+r)*128 + t];
  __syncthreads();
  float a0=b2[0], a1=b2[1];
  for (int ch=0; ch<128; ++ch){
    float v = fmaf(bf2f(tile[t][ch]), sc[ch], bi[ch]);
    v = fmaxf(v, 0.f);
    a0 = fmaf(wa[ch], v, a0);
    a1 = fmaf(wb[ch], v, a1);
  }
  size_t base = (size_t)8*256*2304 + (size_t)head*36864 + (size_t)b*2*2304 + n0 + t;
  dout[base]        = a0;
  dout[base+2304]   = a1;
}

extern "C" void kernel_launch(void* const* d_in, const int* in_sizes, int n_in,
                              void* d_out, int out_size, void* d_ws, size_t ws_size,
                              hipStream_t stream){
  (void)out_size;
  long off[31]; long tot=0;
  int ni = n_in < 31 ? n_in : 31;
  for (int i=0;i<ni;++i){ off[i]=tot; tot += ((long)in_sizes[i]+63)&~63L; }  // 64-elem pad => 16B-aligned float4
  char* ws = (char*)d_ws;
  size_t pos = 0;
  auto alloc = [&](size_t bytes)->char*{
    char* p = ws+pos; pos = (pos + bytes + 255) & ~(size_t)255; return p; };
  int*   FLAG = (int*)alloc(256);
  float* TXTN = (float*)alloc(8*256*4);
  float* AVEC = (float*)alloc(8*256*4);
  float* COS  = (float*)alloc(8*2304*4);
  float* LOGP = (float*)alloc(8*2304*4);
  float* LOGQ = (float*)alloc(8*2304*4);
  float* FV   = (float*)alloc(8*2304*4);
  float* GV   = (float*)alloc(8*2304*4);
  u16*   PJ   = (u16*)alloc(2304*2);
  float* SPT  = (float*)alloc(9025*4);
  float* PQS  = (float*)alloc(8*4*4);
  float* PART = (float*)alloc(2*64*128*2*4);
  float* BNS  = (float*)alloc(2*128*2*4);
  float* PZ   = (float*)alloc((size_t)8*2304*9*4);
  u16* W2P = (u16*)alloc((size_t)36*256*64*2);
  u16* SF  = (u16*)alloc((size_t)8*2304*256*2);
  u16* SN  = (u16*)alloc((size_t)8*2304*256*2);
  u16* SFT = (u16*)alloc((size_t)8*2304*256*2);
  float* FUF = (float*)alloc((size_t)8*2304*256*4);   // f32 accumulator (atomic, 2-way deterministic)
  u16* OFN = (u16*)alloc((size_t)8*2304*256*2);
  u16* H1  = (u16*)alloc((size_t)8*2304*128*2);
  u16* H2  = (u16*)alloc((size_t)8*2304*128*2);
  float* canon = (float*)alloc((size_t)tot*4);
  size_t zslice = (size_t)NTOK*NTOK;           // fp8: 1 byte/elem
  int zsl = (pos + 8*zslice + 256 <= ws_size) ? 8 : 1;
  u8* Z = (u8*)alloc((size_t)zsl*zslice);

  k_detect<<<1,64,0,stream>>>((const u16*)d_in[1], FLAG);
  CanonArgs ca;
  for (int i=0;i<ni;++i){ ca.src[i]=d_in[i]; ca.n[i]=in_sizes[i]; ca.off[i]=(int)off[i]; }
  k_canon<<<dim3(512,(unsigned)ni),256,0,stream>>>(ca, canon, FLAG, ni);
  k_zero<<<4608,256,0,stream>>>(FUF, 8*2304*256/4);

  const float* c_img = canon+off[0];
  const float* c_txt = canon+off[1];
  const float* c_den = canon+off[2];
  const float* c_tpw = canon+off[3];
  const float* c_tpb = canon+off[4];
  const float* c_wv  = canon+off[9];
  const float* c_bv  = canon+off[10];
  const float* c_wo  = canon+off[11];
  const float* c_bo  = canon+off[12];
  const float* c_lng = canon+off[13];
  const float* c_lnb = canon+off[14];
  const float* c_opw = canon+off[15];
  const float* c_opb = canon+off[16];
  const float* c_h1w = canon+off[17];
  const float* c_h1b = canon+off[18];
  const float* c_hbg = canon+off[19];
  const float* c_hbb = canon+off[20];
  const float* c_h2w = canon+off[21];
  const float* c_h2b = canon+off[22];
  const float* c_v1w = canon+off[23];
  const float* c_v1b = canon+off[24];
  const float* c_vbg = canon+off[25];
  const float* c_vbb = canon+off[26];
  const float* c_v2w = canon+off[27];
  const float* c_v2b = canon+off[28];
  const float* c_tmp = canon+off[29];
  const float* c_sw  = canon+off[30];

  k_txt<<<8,256,0,stream>>>(c_txt, c_tpw, c_tpb, c_wv, c_bv, c_wo, c_bo, TXTN, AVEC);
  k_lnfuse<<<dim3(72,8),256,0,stream>>>(c_img, AVEC, c_lng, c_lnb, TXTN, SF, SN, COS);
  k_pqred<<<8,256,0,stream>>>(COS, c_den, c_tmp, PQS);
  k_pqelem<<<80,256,0,stream>>>(COS, c_den, c_tmp, c_sw, PQS, LOGP, LOGQ, GV, PJ, SPT);
  k_packw<<<2304,256,0,stream>>>(c_h1w, c_v1w, W2P);
  k_trans<<<dim3(36,4,8),256,0,stream>>>(SF, SFT);

  if (zsl == 8){
    k_cost<<<dim3(36,9,8),256,0,stream>>>(SN, PJ, SPT, Z, PZ, 0);
    k_sinkred<<<72,256,0,stream>>>(PZ, LOGP, FV, 0, 8);        // fused first f-pass
    for (int it=0; it<3; ++it){
      if (it>0) k_sinkZ<<<dim3(72,8),256,0,stream>>>(Z, GV, LOGP, FV, 0);
      k_sinkZ<<<dim3(72,8),256,0,stream>>>(Z, FV, LOGQ, GV, 0);
    }
    k_applyT<<<dim3(36,NSPL,8),256,0,stream>>>(Z, SFT, FV, GV, FUF, 0);
  } else {
    for (int bi=0; bi<8; ++bi){
      k_cost<<<dim3(36,9,1),256,0,stream>>>(SN, PJ, SPT, Z, PZ, bi);
      k_sinkred<<<9,256,0,stream>>>(PZ, LOGP, FV, bi, 1);
      for (int it=0; it<3; ++it){
        if (it>0) k_sinkZ<<<dim3(72,1),256,0,stream>>>(Z, GV, LOGP, FV, bi);
        k_sinkZ<<<dim3(72,1),256,0,stream>>>(Z, FV, LOGQ, GV, bi);
      }
      k_applyT<<<dim3(36,NSPL,1),256,0,stream>>>(Z, SFT, FV, GV, FUF, bi);
    }
  }

  k_opgemm<<<dim3(36,8),256,0,stream>>>(FUF, c_opw, c_opb, c_img, (float*)d_out, OFN);
  k_conv2<<<dim3(36,8),256,0,stream>>>(OFN, W2P, c_h1b, c_v1b, H1, H2);
  k_stats<<<dim3(64,2),128,0,stream>>>(H1, H2, PART);
  k_statr<<<2,128,0,stream>>>(PART, c_hbg, c_hbb, c_vbg, c_vbb, BNS);
  k_fin<<<dim3(18,8,2),128,0,stream>>>(H1, H2, BNS, c_h2w, c_h2b, c_v2w, c_v2b, (float*)d_out);
}

// Round 7
// 395.794 us; speedup vs baseline: 1.0303x; 1.0303x over previous
//
#include <hip/hip_runtime.h>
#include <hip/hip_bf16.h>

#define NTOK 2304
#define CCH  256
#define BB   8
#define NSPL 2

typedef __attribute__((ext_vector_type(4))) float f32x4;
typedef __attribute__((ext_vector_type(8))) short s16x8;
typedef __attribute__((ext_vector_type(8))) _Float16 h16x8;
typedef unsigned short u16;
typedef unsigned char u8;

__device__ __forceinline__ u16 f2bf(float x){
  union{float f; unsigned u;} v; v.f = x;
  unsigned r = v.u + 0x7fffu + ((v.u>>16)&1u);
  return (u16)(r>>16);
}
__device__ __forceinline__ float bf2f(u16 h){
  union{float f; unsigned u;} v; v.u = ((unsigned)h)<<16; return v.f;
}

// ---- fp8 codec: HW OCP e4m3fn if available, else manual 2^±120 scheme ----
#if __has_builtin(__builtin_amdgcn_cvt_f32_fp8) && __has_builtin(__builtin_amdgcn_cvt_pk_fp8_f32)
#define HWFP8 1
#else
#define HWFP8 0
#endif

__device__ __forceinline__ u8 enc8(float z){
  union{float f; unsigned u;} a; a.f = fabsf(z) * 0x1p-120f;
  unsigned u = a.u + 0x7FFFFu + ((a.u>>20)&1u);
  unsigned b = (u>>20)&0x7Fu;
  if (b > 0x7Eu) b = 0x7Eu;
  return (u8)(b | (z<0.f ? 0x80u : 0u));
}
__device__ __forceinline__ float dec8(unsigned b){
  union{unsigned u; float f;} w;
  w.u = ((b&0x80u)<<24) | ((b&0x7Fu)<<20);
  return w.f * 0x1p120f;
}

#if HWFP8
// builtin needs a LITERAL byte-select; switch folds after unroll+constprop
__device__ __forceinline__ float DEC8(unsigned w, int e){
  switch(e & 3){
    case 0:  return __builtin_amdgcn_cvt_f32_fp8((int)w, 0);
    case 1:  return __builtin_amdgcn_cvt_f32_fp8((int)w, 1);
    case 2:  return __builtin_amdgcn_cvt_f32_fp8((int)w, 2);
    default: return __builtin_amdgcn_cvt_f32_fp8((int)w, 3);
  }
}
__device__ __forceinline__ unsigned pack4(float z0,float z1,float z2,float z3){
  int v = __builtin_amdgcn_cvt_pk_fp8_f32(z0, z1, 0, false);
  v = __builtin_amdgcn_cvt_pk_fp8_f32(z2, z3, v, true);
  return (unsigned)v;
}
#else
__device__ __forceinline__ float DEC8(unsigned w, int e){
  return dec8((w>>(8*(e&3)))&0xFFu);
}
__device__ __forceinline__ unsigned pack4(float z0,float z1,float z2,float z3){
  return (unsigned)enc8(z0) | ((unsigned)enc8(z1)<<8) |
         ((unsigned)enc8(z2)<<16) | ((unsigned)enc8(z3)<<24);
}
#endif

// stored index s within a 256-col block -> true column offset
// s = lc*16 + js*4 + cf  <->  t = js*64 + cf*16 + lc
__device__ __forceinline__ int unperm256(int s){
  return (((s>>2)&3)<<6) + ((s&3)<<4) + (s>>4);
}

// swizzles: rows of 512B (256 bf16), 128B (64 bf16), 64B (32 bf16)
__device__ __forceinline__ int swz512(int row, int b){ return row*512 + (b ^ ((row&7)<<4)); }
__device__ __forceinline__ int swz128(int row, int b){ return row*128 + (b ^ ((row&7)<<4)); }
__device__ __forceinline__ int swz64 (int row, int b){ return row*64  + (b ^ ((row&3)<<4)); }

// async global->LDS, 16B per lane; LDS dest is wave-uniform base + lane*16
__device__ __forceinline__ void gl_lds16(const void* g, void* l){
  __builtin_amdgcn_global_load_lds(
      (const __attribute__((address_space(1))) unsigned int*)g,
      (__attribute__((address_space(3))) unsigned int*)l, 16, 0, 0);
}

struct CanonArgs {
  const void* src[31];
  int n[31];
  int off[31];
};

// ---------------- dtype detect + canonicalize to f32 ----------------
__global__ void k_detect(const u16* probe, int* flag){
  if (threadIdx.x==0){
    int cnt=0;
    for (int i=0;i<16;++i){
      unsigned e = (probe[2*i]>>7)&0xFFu;
      if (e>=100u && e<=140u) ++cnt;
    }
    *flag = (cnt>=14)?1:0;   // 1 => inputs are bf16
  }
}

__global__ __launch_bounds__(256) void k_canon(CanonArgs a, float* dst, const int* flag, int nt){
  int t = blockIdx.y;
  if (t>=nt) return;
  int n = a.n[t];
  const void* s = a.src[t];
  float* d = dst + a.off[t];
  bool isbf = (*flag)!=0;
  int n4 = n >> 2;
  for (int i = blockIdx.x*256+threadIdx.x; i < n4; i += gridDim.x*256){
    if (isbf){
      ushort4 v = ((const ushort4*)s)[i];
      float4 o; o.x=bf2f(v.x); o.y=bf2f(v.y); o.z=bf2f(v.z); o.w=bf2f(v.w);
      ((float4*)d)[i] = o;
    } else {
      ((float4*)d)[i] = ((const float4*)s)[i];
    }
  }
  int base = n4<<2;
  int rem = n - base;
  int i = blockIdx.x*256+threadIdx.x;
  if (i < rem)
    d[base+i] = isbf ? bf2f(((const u16*)s)[base+i]) : ((const float*)s)[base+i];
}

// ---------------- zero f32 buffer ----------------
__global__ __launch_bounds__(256) void k_zero(float* p, int n4){
  int i = blockIdx.x*256+threadIdx.x;
  if (i < n4) ((float4*)p)[i] = (float4){0.f,0.f,0.f,0.f};
}

// ---------------- text path: txt_emb, txt_n, attn_vec ----------------
__global__ __launch_bounds__(256) void k_txt(const float* txt, const float* tpw, const float* tpb,
    const float* wv, const float* bv, const float* wo, const float* bo, float* TXTN, float* AVEC){
  int b=blockIdx.x, t=threadIdx.x;
  __shared__ float sT[512];
  __shared__ float sE[256];
  __shared__ float sV[256];
  __shared__ float red[4];
  sT[t]      = txt[b*512+t];
  sT[t+256]  = txt[b*512+256+t];
  __syncthreads();
  float acc = tpb[t];
  const float* wr = tpw + (size_t)t*512;
  for (int k=0;k<512;++k) acc = fmaf(sT[k], wr[k], acc);
  sE[t] = acc;
  float ss = acc*acc;
  for (int d=1; d<64; d<<=1) ss += __shfl_xor(ss, d);
  if ((t&63)==0) red[t>>6] = ss;
  __syncthreads();
  float nrm = sqrtf(red[0]+red[1]+red[2]+red[3]);
  TXTN[b*256+t] = acc / fmaxf(nrm, 1e-12f);
  float av = bv[t];
  const float* wvr = wv + (size_t)t*256;
  for (int k=0;k<256;++k) av = fmaf(sE[k], wvr[k], av);
  sV[t] = av;
  __syncthreads();
  float ao = bo[t];
  const float* wor = wo + (size_t)t*256;
  for (int k=0;k<256;++k) ao = fmaf(sV[k], wor[k], ao);
  AVEC[b*256+t] = ao;
}

// -------- fused transpose + residual + layernorm + l2norm + cos --------
__global__ __launch_bounds__(256) void k_lnfuse(const float* img, const float* AVEC, const float* lng,
    const float* lnb, const float* TXTN, u16* SF, u16* SN, float* COS){
  int b=blockIdx.y, n0=blockIdx.x*32, t=threadIdx.x;
  __shared__ float xt[32][256];
  float av = AVEC[b*256+t];
  const float* ip = img + ((size_t)b*256 + t)*NTOK + n0;
  #pragma unroll
  for (int j4=0;j4<8;++j4){
    float4 v = *(const float4*)(ip + j4*4);
    xt[j4*4+0][t]=v.x+av; xt[j4*4+1][t]=v.y+av; xt[j4*4+2][t]=v.z+av; xt[j4*4+3][t]=v.w+av;
  }
  int wv_=t>>6, l=t&63;
  float lg[4], lb[4], tn[4];
  #pragma unroll
  for (int k=0;k<4;++k){ lg[k]=lng[l+64*k]; lb[k]=lnb[l+64*k]; tn[k]=TXTN[b*256+l+64*k]; }
  __syncthreads();
  for (int rr=0; rr<8; ++rr){
    int j = wv_*8+rr; int n = n0+j;
    float x[4]; float s=0.f, ss=0.f;
    #pragma unroll
    for (int k=0;k<4;++k){ float v=xt[j][l+64*k]; x[k]=v; s+=v; ss=fmaf(v,v,ss); }
    for (int d=1; d<64; d<<=1){ s += __shfl_xor(s,d); ss += __shfl_xor(ss,d); }
    float mu = s*(1.f/256.f);
    float var = ss*(1.f/256.f) - mu*mu;
    float rstd = rsqrtf(fmaxf(var,0.f)+1e-5f);
    float y[4]; float sy=0.f;
    #pragma unroll
    for (int k=0;k<4;++k){ y[k] = fmaf((x[k]-mu)*rstd, lg[k], lb[k]); sy = fmaf(y[k],y[k],sy); }
    for (int d=1; d<64; d<<=1) sy += __shfl_xor(sy,d);
    float rn = 1.f/fmaxf(sqrtf(sy),1e-12f);
    float cp = 0.f;
    size_t base = ((size_t)b*NTOK + n)*CCH;
    #pragma unroll
    for (int k=0;k<4;++k){
      float sv = y[k]*rn;
      SF[base + l+64*k] = f2bf(y[k]);
      SN[base + l+64*k] = f2bf(sv);
      cp = fmaf(sv, tn[k], cp);
    }
    for (int d=1; d<64; d<<=1) cp += __shfl_xor(cp,d);
    if (l==0) COS[b*NTOK+n] = cp;
  }
}

// -------- per-b reductions for p and q --------
__global__ __launch_bounds__(256) void k_pqred(const float* COS, const float* den, const float* tmpp, float* PQS){
  int b=blockIdx.x, t=threadIdx.x;
  __shared__ float red[256];
  float temp = fmaxf(tmpp[0], 0.01f);
  float mx = -1e30f;
  for (int n=t; n<NTOK; n+=256) mx = fmaxf(mx, COS[b*NTOK+n]);
  red[t]=mx; __syncthreads();
  for (int o=128;o>0;o>>=1){ if (t<o) red[t]=fmaxf(red[t],red[t+o]); __syncthreads(); }
  float maxc = red[0]; __syncthreads();
  float sp=0.f, st=0.f;
  for (int n=t; n<NTOK; n+=256){
    float cv = COS[b*NTOK+n];
    sp += __expf((cv-maxc)/temp)*((cv>0.f)?1.f:0.f)+1e-8f;
    float dv = den[b*NTOK+n];
    st += fmaxf(dv,0.f)+1e-6f;
  }
  red[t]=sp; __syncthreads();
  for (int o=128;o>0;o>>=1){ if (t<o) red[t]+=red[t+o]; __syncthreads(); }
  sp = red[0]; __syncthreads();
  red[t]=st; __syncthreads();
  for (int o=128;o>0;o>>=1){ if (t<o) red[t]+=red[t+o]; __syncthreads(); }
  if (t==0){ PQS[b*4]=maxc; PQS[b*4+1]=sp; PQS[b*4+2]=red[0]; }
}

// Also builds PJ[n] = (n/48)*95 + n%48 (u16) and the 95x95 spatial-cost table
__global__ __launch_bounds__(256) void k_pqelem(const float* COS, const float* den, const float* tmpp,
    const float* swp, const float* PQS, float* LOGP, float* LOGQ, float* GV, u16* PJ, float* SPT){
  int idx = blockIdx.x*256+threadIdx.x;
  float temp = fmaxf(tmpp[0], 0.01f);
  if (idx < BB*NTOK){
    int b = idx / NTOK;
    float maxc = PQS[b*4], sp = PQS[b*4+1], st = PQS[b*4+2];
    float cv = COS[idx];
    float pu = __expf((cv-maxc)/temp)*((cv>0.f)?1.f:0.f)+1e-8f;
    LOGP[idx] = logf(pu/sp + 1e-12f);
    float dv = den[idx];
    LOGQ[idx] = logf((fmaxf(dv,0.f)+1e-6f)/st + 1e-12f);
    GV[idx] = 0.f;
  }
  if (idx < NTOK){
    int h = idx/48, w = idx - h*48;
    PJ[idx] = (u16)(h*95 + w);
  }
  if (idx < 9025){
    int dh = idx/95 - 47, dw = idx - (idx/95)*95 - 47;
    float spw = swp[0]*(20.0f/1.41421356f);
    float dy = (float)dh*(1.f/47.f), dx = (float)dw*(1.f/47.f);
    SPT[idx] = spw*sqrtf(fmaf(dy,dy,dx*dx));
  }
}

// -------- weight repack for conv heads -> chunk-major [36 kc][256 o][64 c] bf16 --------
__global__ __launch_bounds__(256) void k_packw(const float* h1w, const float* v1w, u16* W2P){
  int idx = blockIdx.x*256+threadIdx.x; // < 589824 = 36*16384
  int kc = idx >> 14;
  int rem = idx & 16383;
  int o = rem >> 6;
  int cl = rem & 63;
  int tap = kc >> 2;
  int c = ((kc&3)<<6) + cl;
  int head = o >> 7, oc = o & 127;
  const float* src = head ? v1w : h1w;
  W2P[idx] = f2bf(src[(oc*256 + c)*9 + tap]);
}

// -------- SF transpose: SFT[b][c][nP] = SF[b][true(nP)][c], n permuted within 256-blocks --------
__global__ __launch_bounds__(256) void k_trans(const u16* SF, u16* SFT){
  int n0 = blockIdx.x*256, c0 = blockIdx.y*64, b = blockIdx.z;
  __shared__ u16 tl[64][260];
  int t = threadIdx.x;
  int nl = t>>3, c8 = (t&7)*8;
  #pragma unroll
  for (int p=0;p<8;++p){
    int n = nl + p*32;
    s16x8 v = *(const s16x8*)(SF + ((size_t)(b*NTOK + n0+n)*CCH + c0 + c8));
    #pragma unroll
    for (int e=0;e<8;++e) tl[c8+e][n] = (u16)v[e];
  }
  __syncthreads();
  int cl = t>>3, n8 = (t&7)*8;
  #pragma unroll
  for (int p=0;p<2;++p){
    int c = cl + p*32;
    #pragma unroll
    for (int q=0;q<4;++q){
      int s0 = q*64 + n8;
      union{ s16x8 v; u16 us[8]; } pk;
      #pragma unroll
      for (int e=0;e<8;++e){ int s = s0+e; pk.us[e] = tl[c][unperm256(s)]; }
      *(s16x8*)(SFT + ((size_t)(b*CCH + c0+c)*NTOK + n0 + s0)) = pk.v;
    }
  }
}

// -------- cost build (64x256 tiles), fp8 Z stored col-PERMUTED per 256-block --------
// Pipelined (MFMA -> bar -> STAGE(js+1) -> epilogue -> bar); Z packs buffered in
// registers across all 4 js and stored as ONE uint4/lane/row at the end ->
// 256B fully-contiguous segments (no partial-line RMW amplification).
__global__ __launch_bounds__(256, 5) void k_cost(const u16* SN, const u16* PJ, const float* SPT,
    u8* Z, float* PZ, int b_base){
  int zb = blockIdx.z, b = b_base + zb;
  int i0 = blockIdx.x*64, by = blockIdx.y, j0b = by*256;
  const u16* SNb = SN + (size_t)b*NTOK*CCH;
  u8* Zb = Z + (size_t)zb*NTOK*NTOK;
  __shared__ __align__(16) char Bs[64*512];
  int tid=threadIdx.x, w=tid>>6, l=tid&63, g4=l>>4, lc=l&15;
  const u16* Arow = SNb + (size_t)(i0 + w*16 + lc)*CCH + g4*8;
  s16x8 af[8];
  #pragma unroll
  for (int ks=0; ks<8; ++ks) af[ks] = *(const s16x8*)(Arow + ks*32);
  int mrow = w*16 + g4*4;
  int ipi[4];
  #pragma unroll
  for (int r=0;r<4;++r) ipi[r] = (int)PJ[i0+mrow+r] + 4512;   // +47*95+47
  float Srow[4] = {0.f,0.f,0.f,0.f};
  unsigned pws[4][4];                  // [r][js], statically indexed (js loop unrolled)
  auto STAGE = [&](int js){
    int j0 = j0b + js*64;
    #pragma unroll
    for (int u=0; u<8; ++u){
      int row = u*8 + w*2 + (l>>5);
      int src = ((l&31)*16) ^ ((row&7)<<4);   // pre-swizzled source, linear LDS dest
      gl_lds16((const char*)(SNb + (size_t)(j0+row)*CCH) + src, Bs + u*4096 + w*1024);
    }
  };
  STAGE(0);
  __syncthreads();                      // initial drain, once
  #pragma unroll
  for (int js=0; js<4; ++js){
    int j0 = j0b + js*64;
    f32x4 acc[4];
    #pragma unroll
    for (int cf=0;cf<4;++cf) acc[cf] = (f32x4){0.f,0.f,0.f,0.f};
    #pragma unroll
    for (int ks=0; ks<8; ++ks){
      int kb = ks*64 + g4*16;
      #pragma unroll
      for (int cf=0; cf<4; ++cf){
        s16x8 bb = *(const s16x8*)(Bs + swz512(cf*16+lc, kb));
        acc[cf] = __builtin_amdgcn_mfma_f32_16x16x32_bf16(af[ks], bb, acc[cf], 0,0,0);
      }
    }
    __builtin_amdgcn_sched_barrier(0);
    __builtin_amdgcn_s_barrier();       // all waves done reading Bs
    __builtin_amdgcn_sched_barrier(0);
    if (js < 3) STAGE(js+1);            // stays in flight under the epilogue
    __builtin_amdgcn_sched_barrier(0);
    // ---- epilogue: spatial table + fp8 pack (to regs) + first-pass row sum ----
    float zf[4][4];
    #pragma unroll
    for (int cf=0; cf<4; ++cf){
      int j = j0 + cf*16 + lc;          // TRUE column
      int pjj = (int)PJ[j];
      #pragma unroll
      for (int r=0;r<4;++r){
        float sp = SPT[ipi[r] - pjj];
        zf[cf][r] = (acc[cf][r]-1.0f)*20.0f - sp;
      }
    }
    #pragma unroll
    for (int r=0;r<4;++r){
      unsigned pw = pack4(zf[0][r], zf[1][r], zf[2][r], zf[3][r]);
      Srow[r] += __expf(DEC8(pw,0)) + __expf(DEC8(pw,1))
               + __expf(DEC8(pw,2)) + __expf(DEC8(pw,3));
      pws[r][js] = pw;
    }
    __builtin_amdgcn_sched_barrier(0);
    __builtin_amdgcn_s_barrier();       // staging drained by epilogue's load waits
    __builtin_amdgcn_sched_barrier(0);
  }
  // full-line Z stores: stored s = lc*16 + js*4 + cf within this by-block
  size_t zbase = (size_t)(i0+mrow)*NTOK + j0b + lc*16;
  #pragma unroll
  for (int r=0;r<4;++r){
    uint4 st; st.x=pws[r][0]; st.y=pws[r][1]; st.z=pws[r][2]; st.w=pws[r][3];
    *(uint4*)(Zb + zbase + (size_t)r*NTOK) = st;
  }
  #pragma unroll
  for (int r=0;r<4;++r){
    float s = Srow[r];
    s += __shfl_xor(s,1); s += __shfl_xor(s,2); s += __shfl_xor(s,4); s += __shfl_xor(s,8);
    if (lc==0) PZ[(size_t)(zb*NTOK + i0 + mrow + r)*9 + by] = s;
  }
}

// -------- combine 9 per-block partials -> first f-pass output (max = 0) --------
__global__ __launch_bounds__(256) void k_sinkred(const float* PZ, const float* LOGP, float* FV,
    int b_base, int zcnt){
  int idx = blockIdx.x*256 + threadIdx.x;
  if (idx >= zcnt*NTOK) return;
  int zb = idx / NTOK, row = idx - zb*NTOK, b = b_base + zb;
  const float* p = PZ + (size_t)idx*9;
  float s = 0.f;
  #pragma unroll
  for (int k=0;k<9;++k) s += p[k];
  FV[b*NTOK+row] = 0.05f*(LOGP[b*NTOK+row] - logf(s));
}

// -------- Sinkhorn half-iteration with FIXED shift C, permuted fp8 Z --------
__global__ __launch_bounds__(256) void k_sinkZ(const u8* Z, const float* addv,
    const float* basev, float* outv, int b_base){
  int zb = blockIdx.y, b = b_base + zb, i0 = blockIdx.x*32;
  __shared__ float fs[NTOK];   // filled in STORED (permuted) order
  __shared__ float wm[4];
  int t = threadIdx.x;
  for (int j=t; j<NTOK; j+=256){
    int s = j & 255;
    fs[j] = addv[b*NTOK + (j & ~255) + unperm256(s)]*20.f;
  }
  __syncthreads();
  float m = -1e30f;
  for (int j=t; j<NTOK; j+=256) m = fmaxf(m, fs[j]);
  #pragma unroll
  for (int d=1; d<64; d<<=1) m = fmaxf(m, __shfl_xor(m, d));
  if ((t&63)==0) wm[t>>6] = m;
  __syncthreads();
  float C = fmaxf(fmaxf(wm[0],wm[1]), fmaxf(wm[2],wm[3]));
  __syncthreads();
  for (int j=t; j<NTOK; j+=256) fs[j] -= C;
  __syncthreads();
  int rl = t>>3, q = t&7;
  int row = i0 + rl;
  const u8* zr = Z + ((size_t)zb*NTOK + row)*NTOK;
  float S = 0.f;
  for (int c0 = q*32; c0 < NTOK; c0 += 256){
    uint4 zA = *(const uint4*)(zr + c0);
    uint4 zB = *(const uint4*)(zr + c0 + 16);
    unsigned wd[8] = {zA.x,zA.y,zA.z,zA.w, zB.x,zB.y,zB.z,zB.w};
    float s32 = 0.f;
    #pragma unroll
    for (int k=0;k<8;++k)
      #pragma unroll
      for (int e=0;e<4;++e)
        s32 += __expf(fs[c0 + k*4 + e] + DEC8(wd[k], e));
    S += s32;
  }
  #pragma unroll
  for (int d=1; d<8; d<<=1) S += __shfl_xor(S, d);
  if (q==0)
    outv[b*NTOK+row] = 0.05f*(basev[b*NTOK+row] - (C + logf(S)));
}

// -------- fused[m,c] += sum_n T[n,m]*SF[n,c] over this split's n-range --------
__global__ __launch_bounds__(256, 3) void k_applyT(const u8* Z, const u16* SFT, const float* FVv,
    const float* GVv, float* FUF, int b_base){
  int zb = blockIdx.z, b = b_base + zb, m0 = blockIdx.x*64;
  int sp = blockIdx.y;
  int nbeg = sp*(NTOK/NSPL), nend = nbeg + (NTOK/NSPL);
  __shared__ __align__(16) char WtL[64*128];   // [m][64 nP] bf16, swz128
  __shared__ __align__(16) char BL[256*128];   // [c][64 nP] bf16, swz128 (via pre-swz source)
  __shared__ float gs[64];
  __shared__ float sfv[NTOK/NSPL];             // f*20 in STORED (permuted) order
  int tid=threadIdx.x, w=tid>>6, l=tid&63, g4=l>>4, lc=l&15;
  if (tid<64) gs[tid] = GVv[b*NTOK+m0+tid]*20.f;
  const float* Fv = FVv + b*NTOK;
  for (int j=tid; j<NTOK/NSPL; j+=256){
    int jj = nbeg + j;
    int s = jj & 255;
    sfv[j] = Fv[(jj & ~255) + unperm256(s)]*20.f;
  }
  const u8* Zb = Z + ((size_t)zb*NTOK + m0)*NTOK;
  const u16* SFTb = SFT + (size_t)b*CCH*NTOK;
  f32x4 acc[4][4];
  #pragma unroll
  for (int mf=0;mf<4;++mf)
    #pragma unroll
    for (int cf=0;cf<4;++cf) acc[mf][cf] = (f32x4){0.f,0.f,0.f,0.f};
  int zm = tid>>2, zq = (tid&3)*16;
  int lrow = l>>3;
  int lsrc = ((l&7)*16) ^ (lrow<<4);
  uint4 zwc = *(const uint4*)(Zb + (size_t)zm*NTOK + nbeg + zq);
  for (int n0=nbeg; n0<nend; n0+=64){
    __syncthreads();
    int nn = (n0+64 < nend) ? n0+64 : nbeg;
    uint4 zwn = *(const uint4*)(Zb + (size_t)zm*NTOK + nn + zq);
    #pragma unroll
    for (int u=0; u<8; ++u){
      int row = w*64 + u*8 + lrow;
      gl_lds16((const char*)(SFTb + (size_t)row*NTOK) + n0*2 + lsrc,
               BL + (w*64 + u*8)*128);
    }
    {
      float g20 = gs[zm];
      unsigned wd[4] = {zwc.x, zwc.y, zwc.z, zwc.w};
      union{ s16x8 v; u16 us[8]; } w0, w1;
      int sbase = n0 - nbeg + zq;
      #pragma unroll
      for (int col=0; col<16; ++col){
        float val = __expf(sfv[sbase+col] + g20 + DEC8(wd[col>>2], col&3));
        if (col < 8) w0.us[col] = f2bf(val); else w1.us[col-8] = f2bf(val);
      }
      *(s16x8*)(WtL + swz128(zm, zq*2)) = w0.v;
      *(s16x8*)(WtL + swz128(zm, zq*2+16)) = w1.v;
    }
    __syncthreads();
    #pragma unroll
    for (int kk=0; kk<2; ++kk){
      s16x8 a[4];
      #pragma unroll
      for (int mf=0;mf<4;++mf) a[mf] = *(const s16x8*)(WtL + swz128(mf*16+lc, kk*64 + g4*16));
      #pragma unroll
      for (int cf=0; cf<4; ++cf){
        s16x8 bb = *(const s16x8*)(BL + swz128(w*64+cf*16+lc, kk*64 + g4*16));
        #pragma unroll
        for (int mf=0; mf<4; ++mf)
          acc[mf][cf] = __builtin_amdgcn_mfma_f32_16x16x32_bf16(a[mf], bb, acc[mf][cf], 0,0,0);
      }
    }
    zwc = zwn;
  }
  float* FUb = FUF + (size_t)b*NTOK*CCH;
  #pragma unroll
  for (int mf=0; mf<4; ++mf)
    #pragma unroll
    for (int cf=0; cf<4; ++cf)
      #pragma unroll
      for (int r=0;r<4;++r){
        int m = m0 + mf*16 + g4*4 + r;
        int c = w*64 + cf*16 + lc;
        atomicAdd(&FUb[(size_t)m*CCH + c], acc[mf][cf][r]);
      }
}

// -------- out_feat = img + op_w @ fused + op_b (f32 out); also [b][n][c] bf16 copy --------
__global__ __launch_bounds__(256) void k_opgemm(const float* FUF, const float* opw, const float* opb,
    const float* img, float* dout, u16* OFN){
  int b=blockIdx.y, n0=blockIdx.x*64;
  __shared__ __align__(16) char Am[64*512];
  __shared__ __align__(16) char Bw[256*64];
  int tid=threadIdx.x, w=tid>>6, l=tid&63, g4=l>>4, lc=l&15;
  const float* FUb = FUF + (size_t)b*NTOK*CCH;
  for (int ch=tid; ch<64*32; ch+=256){
    int r=ch>>5, c8=(ch&31)*8;
    const float* fp = FUb + (size_t)(n0+r)*CCH + c8;
    float4 v0 = *(const float4*)fp;
    float4 v1 = *(const float4*)(fp+4);
    union { s16x8 v; u16 us[8]; } pk;
    pk.us[0]=f2bf(v0.x); pk.us[1]=f2bf(v0.y); pk.us[2]=f2bf(v0.z); pk.us[3]=f2bf(v0.w);
    pk.us[4]=f2bf(v1.x); pk.us[5]=f2bf(v1.y); pk.us[6]=f2bf(v1.z); pk.us[7]=f2bf(v1.w);
    *(s16x8*)(Am + swz512(r, c8*2)) = pk.v;
  }
  f32x4 acc[4][4];
  #pragma unroll
  for (int mf=0;mf<4;++mf)
    #pragma unroll
    for (int cf=0;cf<4;++cf) acc[mf][cf] = (f32x4){0.f,0.f,0.f,0.f};
  for (int ks=0; ks<8; ++ks){
    __syncthreads();
    {
      int o = tid;
      const float* wr = opw + (size_t)o*CCH + ks*32;
      #pragma unroll
      for (int u=0; u<4; ++u){
        float4 v0 = *(const float4*)(wr + u*8);
        float4 v1 = *(const float4*)(wr + u*8 + 4);
        union { s16x8 v; u16 us[8]; } pk;
        pk.us[0]=f2bf(v0.x); pk.us[1]=f2bf(v0.y); pk.us[2]=f2bf(v0.z); pk.us[3]=f2bf(v0.w);
        pk.us[4]=f2bf(v1.x); pk.us[5]=f2bf(v1.y); pk.us[6]=f2bf(v1.z); pk.us[7]=f2bf(v1.w);
        *(s16x8*)(Bw + swz64(o, u*16)) = pk.v;
      }
    }
    __syncthreads();
    #pragma unroll
    for (int mf=0; mf<4; ++mf){
      s16x8 a = *(const s16x8*)(Am + swz512(mf*16+lc, (ks*32+g4*8)*2));
      #pragma unroll
      for (int cf=0; cf<4; ++cf){
        int o = w*64+cf*16+lc;
        s16x8 bb = *(const s16x8*)(Bw + swz64(o, g4*16));
        acc[mf][cf] = __builtin_amdgcn_mfma_f32_16x16x32_bf16(a, bb, acc[mf][cf], 0,0,0);
      }
    }
  }
  #pragma unroll
  for (int mf=0; mf<4; ++mf){
    int nl = mf*16 + g4*4; int n = n0+nl;
    #pragma unroll
    for (int cf=0; cf<4; ++cf){
      int o = w*64+cf*16+lc;
      float ob = opb[o];
      const float* ip = img + ((size_t)b*CCH + o)*NTOK + n;
      float4 im = *(const float4*)ip;
      float o0 = acc[mf][cf][0]+ob+im.x;
      float o1 = acc[mf][cf][1]+ob+im.y;
      float o2 = acc[mf][cf][2]+ob+im.z;
      float o3 = acc[mf][cf][3]+ob+im.w;
      float4 st; st.x=o0; st.y=o1; st.z=o2; st.w=o3;
      *(float4*)(dout + ((size_t)b*CCH+o)*NTOK + n) = st;
      u16* ofp = OFN + ((size_t)b*NTOK + n)*CCH + o;
      ofp[0]=f2bf(o0); ofp[CCH]=f2bf(o1); ofp[2*CCH]=f2bf(o2); ofp[3*CCH]=f2bf(o3);
    }
  }
}

// -------- fused conv3x3 heads as LDS-staged implicit GEMM, pipelined --------
__global__ __launch_bounds__(256, 2) void k_conv2(const u16* OFN, const u16* W2P,
    const float* h1b, const float* v1b, u16* H1, u16* H2){
  int b = blockIdx.y, n0 = blockIdx.x*64;
  __shared__ __align__(16) char As[64*128];        // [row][64 K] bf16 swz128
  __shared__ __align__(16) char Ws[2][256*128];    // [o][64 K] bf16 swz128, double buffer
  int tid=threadIdx.x, w=tid>>6, l=tid&63, g4=l>>4, lc=l&15;
  int ar = tid>>2, aseg = (tid&3)*16;
  int arow = n0 + ar;
  int hr = arow/48, wc = arow - hr*48;
  const u16* Ob = OFN + (size_t)b*NTOK*CCH;
  int wrow = tid>>3;
  int wsrc = ((tid&7)*16) ^ ((wrow&7)<<4);
  const char* Wbase = (const char*)W2P;
  f32x4 acc[4][4];
  #pragma unroll
  for (int mf=0;mf<4;++mf)
    #pragma unroll
    for (int of=0;of<4;++of) acc[mf][of] = (f32x4){0.f,0.f,0.f,0.f};
  auto STAGEW = [&](int kc, int buf){
    const char* src = Wbase + (size_t)kc*32768;
    #pragma unroll
    for (int u=0; u<8; ++u)
      gl_lds16(src + (size_t)(u*32 + wrow)*128 + wsrc, Ws[buf] + u*4096 + w*1024);
  };
  auto LOADA = [&](int kc, s16x8& ra0, s16x8& ra1){
    int tap = kc>>2, cq = (kc&3)*64;
    int kh = tap/3;
    int dh = kh-1, dw = (tap-kh*3)-1;
    bool val = ((unsigned)(hr+dh) < 48u) && ((unsigned)(wc+dw) < 48u);
    ra0 = (s16x8){0,0,0,0,0,0,0,0}; ra1 = ra0;
    if (val){
      const u16* ap = Ob + (size_t)(arow + dh*48 + dw)*CCH + cq + aseg;
      ra0 = *(const s16x8*)ap;
      ra1 = *(const s16x8*)(ap+8);
    }
  };
  s16x8 a0, a1, na0, na1;
  STAGEW(0, 0);
  LOADA(0, a0, a1);
  for (int kc=0; kc<36; ++kc){
    int cur = kc & 1;
    __builtin_amdgcn_s_barrier();
    __builtin_amdgcn_sched_barrier(0);
    if (kc+1 < 36){
      STAGEW(kc+1, cur^1);
      LOADA(kc+1, na0, na1);
    }
    *(s16x8*)(As + swz128(ar, aseg*2))    = a0;
    *(s16x8*)(As + swz128(ar, aseg*2+16)) = a1;
    asm volatile("s_waitcnt lgkmcnt(0)" ::: "memory");
    __builtin_amdgcn_s_barrier();
    __builtin_amdgcn_sched_barrier(0);
    #pragma unroll
    for (int ks=0; ks<2; ++ks){
      s16x8 af[4];
      #pragma unroll
      for (int mf=0;mf<4;++mf) af[mf] = *(const s16x8*)(As + swz128(mf*16+lc, ks*64 + g4*16));
      #pragma unroll
      for (int of=0; of<4; ++of){
        s16x8 bf = *(const s16x8*)(Ws[cur] + swz128(w*64+of*16+lc, ks*64 + g4*16));
        #pragma unroll
        for (int mf=0; mf<4; ++mf)
          acc[mf][of] = __builtin_amdgcn_mfma_f32_16x16x32_bf16(af[mf], bf, acc[mf][of], 0,0,0);
      }
    }
    a0 = na0; a1 = na1;
  }
  #pragma unroll
  for (int of=0; of<4; ++of){
    int o = w*64 + of*16 + lc;
    int head = o>>7, oc = o&127;
    float bias = (head? v1b : h1b)[oc];
    u16* Hh = head? H2 : H1;
    #pragma unroll
    for (int mf=0; mf<4; ++mf){
      #pragma unroll
      for (int r=0;r<4;++r){
        int n = n0 + mf*16 + g4*4 + r;
        Hh[((size_t)b*NTOK+n)*128 + oc] = f2bf(acc[mf][of][r] + bias);
      }
    }
  }
}

// -------- BN batch stats (two-stage, deterministic) --------
__global__ __launch_bounds__(128) void k_stats(const u16* H1, const u16* H2, float* PART){
  int head=blockIdx.y, blk=blockIdx.x, t=threadIdx.x;
  const u16* Hh = head? H2:H1;
  float s=0.f, ss=0.f;
  size_t r0 = (size_t)blk*288;
  for (int r=0;r<288;++r){
    float v = bf2f(Hh[(r0+r)*128 + t]);
    s += v; ss = fmaf(v,v,ss);
  }
  PART[((head*64+blk)*128+t)*2]   = s;
  PART[((head*64+blk)*128+t)*2+1] = ss;
}

__global__ __launch_bounds__(128) void k_statr(const float* PART, const float* hbg, const float* hbb,
    const float* vbg, const float* vbb, float* BNS){
  int head=blockIdx.x, t=threadIdx.x;
  float s=0.f, ss=0.f;
  for (int blk=0;blk<64;++blk){
    s  += PART[((head*64+blk)*128+t)*2];
    ss += PART[((head*64+blk)*128+t)*2+1];
  }
  float mean = s*(1.f/18432.f);
  float var = ss*(1.f/18432.f) - mean*mean;
  var = fmaxf(var, 0.f);
  const float* g  = head? vbg:hbg;
  const float* be = head? vbb:hbb;
  float sc = g[t]/sqrtf(var+1e-5f);
  BNS[(head*128+t)*2]   = sc;
  BNS[(head*128+t)*2+1] = be[t] - mean*sc;
}

// -------- BN-normalize + relu + conv1x1(128->2), f32 out --------
__global__ __launch_bounds__(128) void k_fin(const u16* H1, const u16* H2, const float* BNS,
    const float* h2w, const float* h2b, const float* v2w, const float* v2b, float* dout){
  int head = blockIdx.z, b = blockIdx.y, n0 = blockIdx.x*128, t=threadIdx.x;
  const u16* Hh = head? H2:H1;
  const float* w2 = head? v2w:h2w;
  const float* b2 = head? v2b:h2b;
  __shared__ u16 tile[128][130];
  __shared__ float sc[128], bi[128], wa[128], wb[128];
  sc[t]=BNS[(head*128+t)*2]; bi[t]=BNS[(head*128+t)*2+1];
  wa[t]=w2[t]; wb[t]=w2[128+t];
  for (int r=0;r<128;++r) tile[r][t] = Hh[((size_t)b*NTOK+n0+r)*128 + t];
  __syncthreads();
  float a0=b2[0], a1=b2[1];
  for (int ch=0; ch<128; ++ch){
    float v = fmaf(bf2f(tile[t][ch]), sc[ch], bi[ch]);
    v = fmaxf(v, 0.f);
    a0 = fmaf(wa[ch], v, a0);
    a1 = fmaf(wb[ch], v, a1);
  }
  size_t base = (size_t)8*256*2304 + (size_t)head*36864 + (size_t)b*2*2304 + n0 + t;
  dout[base]        = a0;
  dout[base+2304]   = a1;
}

extern "C" void kernel_launch(void* const* d_in, const int* in_sizes, int n_in,
                              void* d_out, int out_size, void* d_ws, size_t ws_size,
                              hipStream_t stream){
  (void)out_size;
  long off[31]; long tot=0;
  int ni = n_in < 31 ? n_in : 31;
  for (int i=0;i<ni;++i){ off[i]=tot; tot += ((long)in_sizes[i]+63)&~63L; }  // 64-elem pad => 16B-aligned float4
  char* ws = (char*)d_ws;
  size_t pos = 0;
  auto alloc = [&](size_t bytes)->char*{
    char* p = ws+pos; pos = (pos + bytes + 255) & ~(size_t)255; return p; };
  int*   FLAG = (int*)alloc(256);
  float* TXTN = (float*)alloc(8*256*4);
  float* AVEC = (float*)alloc(8*256*4);
  float* COS  = (float*)alloc(8*2304*4);
  float* LOGP = (float*)alloc(8*2304*4);
  float* LOGQ = (float*)alloc(8*2304*4);
  float* FV   = (float*)alloc(8*2304*4);
  float* GV   = (float*)alloc(8*2304*4);
  u16*   PJ   = (u16*)alloc(2304*2);
  float* SPT  = (float*)alloc(9025*4);
  float* PQS  = (float*)alloc(8*4*4);
  float* PART = (float*)alloc(2*64*128*2*4);
  float* BNS  = (float*)alloc(2*128*2*4);
  float* PZ   = (float*)alloc((size_t)8*2304*9*4);
  u16* W2P = (u16*)alloc((size_t)36*256*64*2);
  u16* SF  = (u16*)alloc((size_t)8*2304*256*2);
  u16* SN  = (u16*)alloc((size_t)8*2304*256*2);
  u16* SFT = (u16*)alloc((size_t)8*2304*256*2);
  float* FUF = (float*)alloc((size_t)8*2304*256*4);   // f32 accumulator (atomic, 2-way deterministic)
  u16* OFN = (u16*)alloc((size_t)8*2304*256*2);
  u16* H1  = (u16*)alloc((size_t)8*2304*128*2);
  u16* H2  = (u16*)alloc((size_t)8*2304*128*2);
  float* canon = (float*)alloc((size_t)tot*4);
  size_t zslice = (size_t)NTOK*NTOK;           // fp8: 1 byte/elem
  int zsl = (pos + 8*zslice + 256 <= ws_size) ? 8 : 1;
  u8* Z = (u8*)alloc((size_t)zsl*zslice);

  k_detect<<<1,64,0,stream>>>((const u16*)d_in[1], FLAG);
  CanonArgs ca;
  for (int i=0;i<ni;++i){ ca.src[i]=d_in[i]; ca.n[i]=in_sizes[i]; ca.off[i]=(int)off[i]; }
  k_canon<<<dim3(512,(unsigned)ni),256,0,stream>>>(ca, canon, FLAG, ni);
  k_zero<<<4608,256,0,stream>>>(FUF, 8*2304*256/4);

  const float* c_img = canon+off[0];
  const float* c_txt = canon+off[1];
  const float* c_den = canon+off[2];
  const float* c_tpw = canon+off[3];
  const float* c_tpb = canon+off[4];
  const float* c_wv  = canon+off[9];
  const float* c_bv  = canon+off[10];
  const float* c_wo  = canon+off[11];
  const float* c_bo  = canon+off[12];
  const float* c_lng = canon+off[13];
  const float* c_lnb = canon+off[14];
  const float* c_opw = canon+off[15];
  const float* c_opb = canon+off[16];
  const float* c_h1w = canon+off[17];
  const float* c_h1b = canon+off[18];
  const float* c_hbg = canon+off[19];
  const float* c_hbb = canon+off[20];
  const float* c_h2w = canon+off[21];
  const float* c_h2b = canon+off[22];
  const float* c_v1w = canon+off[23];
  const float* c_v1b = canon+off[24];
  const float* c_vbg = canon+off[25];
  const float* c_vbb = canon+off[26];
  const float* c_v2w = canon+off[27];
  const float* c_v2b = canon+off[28];
  const float* c_tmp = canon+off[29];
  const float* c_sw  = canon+off[30];

  k_txt<<<8,256,0,stream>>>(c_txt, c_tpw, c_tpb, c_wv, c_bv, c_wo, c_bo, TXTN, AVEC);
  k_lnfuse<<<dim3(72,8),256,0,stream>>>(c_img, AVEC, c_lng, c_lnb, TXTN, SF, SN, COS);
  k_pqred<<<8,256,0,stream>>>(COS, c_den, c_tmp, PQS);
  k_pqelem<<<80,256,0,stream>>>(COS, c_den, c_tmp, c_sw, PQS, LOGP, LOGQ, GV, PJ, SPT);
  k_packw<<<2304,256,0,stream>>>(c_h1w, c_v1w, W2P);
  k_trans<<<dim3(9,4,8),256,0,stream>>>(SF, SFT);

  if (zsl == 8){
    k_cost<<<dim3(36,9,8),256,0,stream>>>(SN, PJ, SPT, Z, PZ, 0);
    k_sinkred<<<72,256,0,stream>>>(PZ, LOGP, FV, 0, 8);        // fused first f-pass
    for (int it=0; it<3; ++it){
      if (it>0) k_sinkZ<<<dim3(72,8),256,0,stream>>>(Z, GV, LOGP, FV, 0);
      k_sinkZ<<<dim3(72,8),256,0,stream>>>(Z, FV, LOGQ, GV, 0);
    }
    k_applyT<<<dim3(36,NSPL,8),256,0,stream>>>(Z, SFT, FV, GV, FUF, 0);
  } else {
    for (int bi=0; bi<8; ++bi){
      k_cost<<<dim3(36,9,1),256,0,stream>>>(SN, PJ, SPT, Z, PZ, bi);
      k_sinkred<<<9,256,0,stream>>>(PZ, LOGP, FV, bi, 1);
      for (int it=0; it<3; ++it){
        if (it>0) k_sinkZ<<<dim3(72,1),256,0,stream>>>(Z, GV, LOGP, FV, bi);
        k_sinkZ<<<dim3(72,1),256,0,stream>>>(Z, FV, LOGQ, GV, bi);
      }
      k_applyT<<<dim3(36,NSPL,1),256,0,stream>>>(Z, SFT, FV, GV, FUF, bi);
    }
  }

  k_opgemm<<<dim3(36,8),256,0,stream>>>(FUF, c_opw, c_opb, c_img, (float*)d_out, OFN);
  k_conv2<<<dim3(36,8),256,0,stream>>>(OFN, W2P, c_h1b, c_v1b, H1, H2);
  k_stats<<<dim3(64,2),128,0,stream>>>(H1, H2, PART);
  k_statr<<<2,128,0,stream>>>(PART, c_hbg, c_hbb, c_vbg, c_vbb, BNS);
  k_fin<<<dim3(18,8,2),128,0,stream>>>(H1, H2, BNS, c_h2w, c_h2b, c_v2w, c_v2b, (float*)d_out);
}

// Round 8
// 370.402 us; speedup vs baseline: 1.1009x; 1.0686x over previous
//
#include <hip/hip_runtime.h>
#include <hip/hip_bf16.h>

#define NTOK 2304
#define CCH  256
#define BB   8
#define NSPL 2

typedef __attribute__((ext_vector_type(4))) float f32x4;
typedef __attribute__((ext_vector_type(8))) short s16x8;
typedef __attribute__((ext_vector_type(8))) _Float16 h16x8;
typedef unsigned short u16;
typedef unsigned char u8;

__device__ __forceinline__ u16 f2bf(float x){
  union{float f; unsigned u;} v; v.f = x;
  unsigned r = v.u + 0x7fffu + ((v.u>>16)&1u);
  return (u16)(r>>16);
}
__device__ __forceinline__ float bf2f(u16 h){
  union{float f; unsigned u;} v; v.u = ((unsigned)h)<<16; return v.f;
}

// ---- fp8 codec: HW OCP e4m3fn if available, else manual 2^±120 scheme ----
#if __has_builtin(__builtin_amdgcn_cvt_f32_fp8) && __has_builtin(__builtin_amdgcn_cvt_pk_fp8_f32)
#define HWFP8 1
#else
#define HWFP8 0
#endif

__device__ __forceinline__ u8 enc8(float z){
  union{float f; unsigned u;} a; a.f = fabsf(z) * 0x1p-120f;
  unsigned u = a.u + 0x7FFFFu + ((a.u>>20)&1u);
  unsigned b = (u>>20)&0x7Fu;
  if (b > 0x7Eu) b = 0x7Eu;
  return (u8)(b | (z<0.f ? 0x80u : 0u));
}
__device__ __forceinline__ float dec8(unsigned b){
  union{unsigned u; float f;} w;
  w.u = ((b&0x80u)<<24) | ((b&0x7Fu)<<20);
  return w.f * 0x1p120f;
}

#if HWFP8
// builtin needs a LITERAL byte-select; switch folds after unroll+constprop
__device__ __forceinline__ float DEC8(unsigned w, int e){
  switch(e & 3){
    case 0:  return __builtin_amdgcn_cvt_f32_fp8((int)w, 0);
    case 1:  return __builtin_amdgcn_cvt_f32_fp8((int)w, 1);
    case 2:  return __builtin_amdgcn_cvt_f32_fp8((int)w, 2);
    default: return __builtin_amdgcn_cvt_f32_fp8((int)w, 3);
  }
}
__device__ __forceinline__ unsigned pack4(float z0,float z1,float z2,float z3){
  int v = __builtin_amdgcn_cvt_pk_fp8_f32(z0, z1, 0, false);
  v = __builtin_amdgcn_cvt_pk_fp8_f32(z2, z3, v, true);
  return (unsigned)v;
}
#else
__device__ __forceinline__ float DEC8(unsigned w, int e){
  return dec8((w>>(8*(e&3)))&0xFFu);
}
__device__ __forceinline__ unsigned pack4(float z0,float z1,float z2,float z3){
  return (unsigned)enc8(z0) | ((unsigned)enc8(z1)<<8) |
         ((unsigned)enc8(z2)<<16) | ((unsigned)enc8(z3)<<24);
}
#endif

// swizzles: rows of 512B (256 bf16), 128B (64 bf16), 64B (32 bf16)
__device__ __forceinline__ int swz512(int row, int b){ return row*512 + (b ^ ((row&7)<<4)); }
__device__ __forceinline__ int swz128(int row, int b){ return row*128 + (b ^ ((row&7)<<4)); }
__device__ __forceinline__ int swz64 (int row, int b){ return row*64  + (b ^ ((row&3)<<4)); }

// async global->LDS, 16B per lane; LDS dest is wave-uniform base + lane*16
__device__ __forceinline__ void gl_lds16(const void* g, void* l){
  __builtin_amdgcn_global_load_lds(
      (const __attribute__((address_space(1))) unsigned int*)g,
      (__attribute__((address_space(3))) unsigned int*)l, 16, 0, 0);
}

struct CanonArgs {
  const void* src[31];
  int n[31];
  int off[31];
};

// ---------------- dtype detect + canonicalize to f32 ----------------
__global__ void k_detect(const u16* probe, int* flag){
  if (threadIdx.x==0){
    int cnt=0;
    for (int i=0;i<16;++i){
      unsigned e = (probe[2*i]>>7)&0xFFu;
      if (e>=100u && e<=140u) ++cnt;
    }
    *flag = (cnt>=14)?1:0;   // 1 => inputs are bf16
  }
}

__global__ __launch_bounds__(256) void k_canon(CanonArgs a, float* dst, const int* flag, int nt){
  int t = blockIdx.y;
  if (t>=nt) return;
  int n = a.n[t];
  const void* s = a.src[t];
  float* d = dst + a.off[t];
  bool isbf = (*flag)!=0;
  int n4 = n >> 2;
  for (int i = blockIdx.x*256+threadIdx.x; i < n4; i += gridDim.x*256){
    if (isbf){
      ushort4 v = ((const ushort4*)s)[i];
      float4 o; o.x=bf2f(v.x); o.y=bf2f(v.y); o.z=bf2f(v.z); o.w=bf2f(v.w);
      ((float4*)d)[i] = o;
    } else {
      ((float4*)d)[i] = ((const float4*)s)[i];
    }
  }
  int base = n4<<2;
  int rem = n - base;
  int i = blockIdx.x*256+threadIdx.x;
  if (i < rem)
    d[base+i] = isbf ? bf2f(((const u16*)s)[base+i]) : ((const float*)s)[base+i];
}

// ---------------- zero f32 buffer ----------------
__global__ __launch_bounds__(256) void k_zero(float* p, int n4){
  int i = blockIdx.x*256+threadIdx.x;
  if (i < n4) ((float4*)p)[i] = (float4){0.f,0.f,0.f,0.f};
}

// ---------------- text path: txt_emb, txt_n, attn_vec ----------------
__global__ __launch_bounds__(256) void k_txt(const float* txt, const float* tpw, const float* tpb,
    const float* wv, const float* bv, const float* wo, const float* bo, float* TXTN, float* AVEC){
  int b=blockIdx.x, t=threadIdx.x;
  __shared__ float sT[512];
  __shared__ float sE[256];
  __shared__ float sV[256];
  __shared__ float red[4];
  sT[t]      = txt[b*512+t];
  sT[t+256]  = txt[b*512+256+t];
  __syncthreads();
  float acc = tpb[t];
  const float* wr = tpw + (size_t)t*512;
  for (int k=0;k<512;++k) acc = fmaf(sT[k], wr[k], acc);
  sE[t] = acc;
  float ss = acc*acc;
  for (int d=1; d<64; d<<=1) ss += __shfl_xor(ss, d);
  if ((t&63)==0) red[t>>6] = ss;
  __syncthreads();
  float nrm = sqrtf(red[0]+red[1]+red[2]+red[3]);
  TXTN[b*256+t] = acc / fmaxf(nrm, 1e-12f);
  float av = bv[t];
  const float* wvr = wv + (size_t)t*256;
  for (int k=0;k<256;++k) av = fmaf(sE[k], wvr[k], av);
  sV[t] = av;
  __syncthreads();
  float ao = bo[t];
  const float* wor = wo + (size_t)t*256;
  for (int k=0;k<256;++k) ao = fmaf(sV[k], wor[k], ao);
  AVEC[b*256+t] = ao;
}

// -------- fused transpose + residual + layernorm + l2norm + cos --------
__global__ __launch_bounds__(256) void k_lnfuse(const float* img, const float* AVEC, const float* lng,
    const float* lnb, const float* TXTN, u16* SF, u16* SN, float* COS){
  int b=blockIdx.y, n0=blockIdx.x*32, t=threadIdx.x;
  __shared__ float xt[32][256];
  float av = AVEC[b*256+t];
  const float* ip = img + ((size_t)b*256 + t)*NTOK + n0;
  #pragma unroll
  for (int j4=0;j4<8;++j4){
    float4 v = *(const float4*)(ip + j4*4);
    xt[j4*4+0][t]=v.x+av; xt[j4*4+1][t]=v.y+av; xt[j4*4+2][t]=v.z+av; xt[j4*4+3][t]=v.w+av;
  }
  int wv_=t>>6, l=t&63;
  float lg[4], lb[4], tn[4];
  #pragma unroll
  for (int k=0;k<4;++k){ lg[k]=lng[l+64*k]; lb[k]=lnb[l+64*k]; tn[k]=TXTN[b*256+l+64*k]; }
  __syncthreads();
  for (int rr=0; rr<8; ++rr){
    int j = wv_*8+rr; int n = n0+j;
    float x[4]; float s=0.f, ss=0.f;
    #pragma unroll
    for (int k=0;k<4;++k){ float v=xt[j][l+64*k]; x[k]=v; s+=v; ss=fmaf(v,v,ss); }
    for (int d=1; d<64; d<<=1){ s += __shfl_xor(s,d); ss += __shfl_xor(ss,d); }
    float mu = s*(1.f/256.f);
    float var = ss*(1.f/256.f) - mu*mu;
    float rstd = rsqrtf(fmaxf(var,0.f)+1e-5f);
    float y[4]; float sy=0.f;
    #pragma unroll
    for (int k=0;k<4;++k){ y[k] = fmaf((x[k]-mu)*rstd, lg[k], lb[k]); sy = fmaf(y[k],y[k],sy); }
    for (int d=1; d<64; d<<=1) sy += __shfl_xor(sy,d);
    float rn = 1.f/fmaxf(sqrtf(sy),1e-12f);
    float cp = 0.f;
    size_t base = ((size_t)b*NTOK + n)*CCH;
    #pragma unroll
    for (int k=0;k<4;++k){
      float sv = y[k]*rn;
      SF[base + l+64*k] = f2bf(y[k]);
      SN[base + l+64*k] = f2bf(sv);
      cp = fmaf(sv, tn[k], cp);
    }
    for (int d=1; d<64; d<<=1) cp += __shfl_xor(cp,d);
    if (l==0) COS[b*NTOK+n] = cp;
  }
}

// -------- per-b reductions for p and q --------
__global__ __launch_bounds__(256) void k_pqred(const float* COS, const float* den, const float* tmpp, float* PQS){
  int b=blockIdx.x, t=threadIdx.x;
  __shared__ float red[256];
  float temp = fmaxf(tmpp[0], 0.01f);
  float mx = -1e30f;
  for (int n=t; n<NTOK; n+=256) mx = fmaxf(mx, COS[b*NTOK+n]);
  red[t]=mx; __syncthreads();
  for (int o=128;o>0;o>>=1){ if (t<o) red[t]=fmaxf(red[t],red[t+o]); __syncthreads(); }
  float maxc = red[0]; __syncthreads();
  float sp=0.f, st=0.f;
  for (int n=t; n<NTOK; n+=256){
    float cv = COS[b*NTOK+n];
    sp += __expf((cv-maxc)/temp)*((cv>0.f)?1.f:0.f)+1e-8f;
    float dv = den[b*NTOK+n];
    st += fmaxf(dv,0.f)+1e-6f;
  }
  red[t]=sp; __syncthreads();
  for (int o=128;o>0;o>>=1){ if (t<o) red[t]+=red[t+o]; __syncthreads(); }
  sp = red[0]; __syncthreads();
  red[t]=st; __syncthreads();
  for (int o=128;o>0;o>>=1){ if (t<o) red[t]+=red[t+o]; __syncthreads(); }
  if (t==0){ PQS[b*4]=maxc; PQS[b*4+1]=sp; PQS[b*4+2]=red[0]; }
}

// Also builds PJ[n] = (n/48)*95 + n%48 (u16) and the 95x95 spatial-cost table
__global__ __launch_bounds__(256) void k_pqelem(const float* COS, const float* den, const float* tmpp,
    const float* swp, const float* PQS, float* LOGP, float* LOGQ, float* GV, u16* PJ, float* SPT){
  int idx = blockIdx.x*256+threadIdx.x;
  float temp = fmaxf(tmpp[0], 0.01f);
  if (idx < BB*NTOK){
    int b = idx / NTOK;
    float maxc = PQS[b*4], sp = PQS[b*4+1], st = PQS[b*4+2];
    float cv = COS[idx];
    float pu = __expf((cv-maxc)/temp)*((cv>0.f)?1.f:0.f)+1e-8f;
    LOGP[idx] = logf(pu/sp + 1e-12f);
    float dv = den[idx];
    LOGQ[idx] = logf((fmaxf(dv,0.f)+1e-6f)/st + 1e-12f);
    GV[idx] = 0.f;
  }
  if (idx < NTOK){
    int h = idx/48, w = idx - h*48;
    PJ[idx] = (u16)(h*95 + w);
  }
  if (idx < 9025){
    int dh = idx/95 - 47, dw = idx - (idx/95)*95 - 47;
    float spw = swp[0]*(20.0f/1.41421356f);
    float dy = (float)dh*(1.f/47.f), dx = (float)dw*(1.f/47.f);
    SPT[idx] = spw*sqrtf(fmaf(dy,dy,dx*dx));
  }
}

// -------- weight repack for conv heads -> chunk-major [36 kc][256 o][64 c] bf16 --------
__global__ __launch_bounds__(256) void k_packw(const float* h1w, const float* v1w, u16* W2P){
  int idx = blockIdx.x*256+threadIdx.x; // < 589824 = 36*16384
  int kc = idx >> 14;
  int rem = idx & 16383;
  int o = rem >> 6;
  int cl = rem & 63;
  int tap = kc >> 2;
  int c = ((kc&3)<<6) + cl;
  int head = o >> 7, oc = o & 127;
  const float* src = head ? v1w : h1w;
  W2P[idx] = f2bf(src[(oc*256 + c)*9 + tap]);
}

// -------- SF transpose: SFT[b][c][nP] = SF[b][true(nP)][c], n permuted within 64-blocks --------
// stored p <-> true t within 64-block: t = (p&3)*16 + (p>>2)   (p = (t&15)*4 + (t>>4))
__global__ __launch_bounds__(256) void k_trans(const u16* SF, u16* SFT){
  int n0 = blockIdx.x*64, c0 = blockIdx.y*64, b = blockIdx.z;
  __shared__ u16 tl[64][68];
  int t = threadIdx.x;
  int nl = t>>3, c8 = (t&7)*8;
  #pragma unroll
  for (int p=0;p<2;++p){
    int n = nl + p*32;
    s16x8 v = *(const s16x8*)(SF + ((size_t)(b*NTOK + n0+n)*CCH + c0 + c8));
    #pragma unroll
    for (int e=0;e<8;++e) tl[c8+e][n] = (u16)v[e];
  }
  __syncthreads();
  int cl = t>>3, n8 = (t&7)*8;
  #pragma unroll
  for (int p=0;p<2;++p){
    int c = cl + p*32;
    union{ s16x8 v; u16 us[8]; } pk;
    #pragma unroll
    for (int e=0;e<8;++e){ int s = n8+e; pk.us[e] = tl[c][((s&3)<<4) | (s>>2)]; }
    *(s16x8*)(SFT + ((size_t)(b*CCH + c0+c)*NTOK + n0 + n8)) = pk.v;
  }
}

// -------- cost build (64x256 tiles), fp8 Z stored col-PERMUTED per 64-block --------
// R5-proven structure (drain barriers, per-js 64B stores, 4 blocks/CU) with the
// spatial sqrt replaced by the precomputed SPT table (coalesced gather).
__global__ __launch_bounds__(256, 4) void k_cost(const u16* SN, const u16* PJ, const float* SPT,
    u8* Z, float* PZ, int b_base){
  int zb = blockIdx.z, b = b_base + zb;
  int i0 = blockIdx.x*64, by = blockIdx.y, j0b = by*256;
  const u16* SNb = SN + (size_t)b*NTOK*CCH;
  u8* Zb = Z + (size_t)zb*NTOK*NTOK;
  __shared__ __align__(16) char Bs[64*512];
  int tid=threadIdx.x, w=tid>>6, l=tid&63, g4=l>>4, lc=l&15;
  const u16* Arow = SNb + (size_t)(i0 + w*16 + lc)*CCH + g4*8;
  s16x8 af[8];
  #pragma unroll
  for (int ks=0; ks<8; ++ks) af[ks] = *(const s16x8*)(Arow + ks*32);
  int mrow = w*16 + g4*4;
  int ipi[4];
  #pragma unroll
  for (int r=0;r<4;++r) ipi[r] = (int)PJ[i0+mrow+r] + 4512;   // +47*95+47
  float Srow[4] = {0.f,0.f,0.f,0.f};
  for (int js=0; js<4; ++js){
    int j0 = j0b + js*64;
    __syncthreads();   // prev MFMA reads of Bs done
    #pragma unroll
    for (int u=0; u<8; ++u){
      int row = u*8 + w*2 + (l>>5);
      int src = ((l&31)*16) ^ ((row&7)<<4);   // pre-swizzled source, linear LDS dest
      gl_lds16((const char*)(SNb + (size_t)(j0+row)*CCH) + src, Bs + u*4096 + w*1024);
    }
    __syncthreads();   // staging complete (vmcnt drained by barrier)
    f32x4 acc[4];
    #pragma unroll
    for (int cf=0;cf<4;++cf) acc[cf] = (f32x4){0.f,0.f,0.f,0.f};
    #pragma unroll
    for (int ks=0; ks<8; ++ks){
      int kb = ks*64 + g4*16;
      #pragma unroll
      for (int cf=0; cf<4; ++cf){
        s16x8 bb = *(const s16x8*)(Bs + swz512(cf*16+lc, kb));
        acc[cf] = __builtin_amdgcn_mfma_f32_16x16x32_bf16(af[ks], bb, acc[cf], 0,0,0);
      }
    }
    float zf[4][4];
    #pragma unroll
    for (int cf=0; cf<4; ++cf){
      int j = j0 + cf*16 + lc;          // TRUE column
      int pjj = (int)PJ[j];
      #pragma unroll
      for (int r=0;r<4;++r){
        float sp = SPT[ipi[r] - pjj];
        zf[cf][r] = (acc[cf][r]-1.0f)*20.0f - sp;
      }
    }
    size_t zrow = (size_t)(i0+mrow)*NTOK + j0 + lc*4;   // stored (permuted) position
    #pragma unroll
    for (int r=0;r<4;++r){
      unsigned pw = pack4(zf[0][r], zf[1][r], zf[2][r], zf[3][r]);
      Srow[r] += __expf(DEC8(pw,0)) + __expf(DEC8(pw,1))
               + __expf(DEC8(pw,2)) + __expf(DEC8(pw,3));
      *(unsigned*)(Zb + zrow + (size_t)r*NTOK) = pw;
    }
  }
  #pragma unroll
  for (int r=0;r<4;++r){
    float s = Srow[r];
    s += __shfl_xor(s,1); s += __shfl_xor(s,2); s += __shfl_xor(s,4); s += __shfl_xor(s,8);
    if (lc==0) PZ[(size_t)(zb*NTOK + i0 + mrow + r)*9 + by] = s;
  }
}

// -------- combine 9 per-block partials -> first f-pass output (max = 0) --------
__global__ __launch_bounds__(256) void k_sinkred(const float* PZ, const float* LOGP, float* FV,
    int b_base, int zcnt){
  int idx = blockIdx.x*256 + threadIdx.x;
  if (idx >= zcnt*NTOK) return;
  int zb = idx / NTOK, row = idx - zb*NTOK, b = b_base + zb;
  const float* p = PZ + (size_t)idx*9;
  float s = 0.f;
  #pragma unroll
  for (int k=0;k<9;++k) s += p[k];
  FV[b*NTOK+row] = 0.05f*(LOGP[b*NTOK+row] - logf(s));
}

// -------- Sinkhorn half-iteration with FIXED shift C, permuted fp8 Z --------
// 32 rows/block, 8 lanes/row; C folded into fs once.
__global__ __launch_bounds__(256) void k_sinkZ(const u8* Z, const float* addv,
    const float* basev, float* outv, int b_base){
  int zb = blockIdx.y, b = b_base + zb, i0 = blockIdx.x*32;
  __shared__ float fs[NTOK];   // filled in STORED (permuted) order
  __shared__ float wm[4];
  int t = threadIdx.x;
  for (int j=t; j<NTOK; j+=256){
    int p = j & 63, tt = ((p&3)<<4) | (p>>2);
    fs[j] = addv[b*NTOK + (j & ~63) + tt]*20.f;
  }
  __syncthreads();
  float m = -1e30f;
  for (int j=t; j<NTOK; j+=256) m = fmaxf(m, fs[j]);
  #pragma unroll
  for (int d=1; d<64; d<<=1) m = fmaxf(m, __shfl_xor(m, d));
  if ((t&63)==0) wm[t>>6] = m;
  __syncthreads();
  float C = fmaxf(fmaxf(wm[0],wm[1]), fmaxf(wm[2],wm[3]));
  __syncthreads();
  for (int j=t; j<NTOK; j+=256) fs[j] -= C;
  __syncthreads();
  int rl = t>>3, q = t&7;
  int row = i0 + rl;
  const u8* zr = Z + ((size_t)zb*NTOK + row)*NTOK;
  float S = 0.f;
  for (int c0 = q*32; c0 < NTOK; c0 += 256){
    uint4 zA = *(const uint4*)(zr + c0);
    uint4 zB = *(const uint4*)(zr + c0 + 16);
    unsigned wd[8] = {zA.x,zA.y,zA.z,zA.w, zB.x,zB.y,zB.z,zB.w};
    float s32 = 0.f;
    #pragma unroll
    for (int k=0;k<8;++k)
      #pragma unroll
      for (int e=0;e<4;++e)
        s32 += __expf(fs[c0 + k*4 + e] + DEC8(wd[k], e));
    S += s32;
  }
  #pragma unroll
  for (int d=1; d<8; d<<=1) S += __shfl_xor(S, d);
  if (q==0)
    outv[b*NTOK+row] = 0.05f*(basev[b*NTOK+row] - (C + logf(S)));
}

// -------- fused[m,c] += sum_n T[n,m]*SF[n,c] over this split's n-range --------
__global__ __launch_bounds__(256, 3) void k_applyT(const u8* Z, const u16* SFT, const float* FVv,
    const float* GVv, float* FUF, int b_base){
  int zb = blockIdx.z, b = b_base + zb, m0 = blockIdx.x*64;
  int sp = blockIdx.y;
  int nbeg = sp*(NTOK/NSPL), nend = nbeg + (NTOK/NSPL);
  __shared__ __align__(16) char WtL[64*128];   // [m][64 nP] bf16, swz128
  __shared__ __align__(16) char BL[256*128];   // [c][64 nP] bf16, swz128 (via pre-swz source)
  __shared__ float gs[64];
  __shared__ float sfv[NTOK/NSPL];             // f*20 in STORED (permuted) order
  int tid=threadIdx.x, w=tid>>6, l=tid&63, g4=l>>4, lc=l&15;
  if (tid<64) gs[tid] = GVv[b*NTOK+m0+tid]*20.f;
  const float* Fv = FVv + b*NTOK;
  for (int j=tid; j<NTOK/NSPL; j+=256){
    int jj = nbeg + j;
    int p = jj & 63, tt = ((p&3)<<4) | (p>>2);
    sfv[j] = Fv[(jj & ~63) + tt]*20.f;
  }
  const u8* Zb = Z + ((size_t)zb*NTOK + m0)*NTOK;
  const u16* SFTb = SFT + (size_t)b*CCH*NTOK;
  f32x4 acc[4][4];
  #pragma unroll
  for (int mf=0;mf<4;++mf)
    #pragma unroll
    for (int cf=0;cf<4;++cf) acc[mf][cf] = (f32x4){0.f,0.f,0.f,0.f};
  int zm = tid>>2, zq = (tid&3)*16;
  int lrow = l>>3;
  int lsrc = ((l&7)*16) ^ (lrow<<4);
  uint4 zwc = *(const uint4*)(Zb + (size_t)zm*NTOK + nbeg + zq);
  for (int n0=nbeg; n0<nend; n0+=64){
    __syncthreads();
    int nn = (n0+64 < nend) ? n0+64 : nbeg;
    uint4 zwn = *(const uint4*)(Zb + (size_t)zm*NTOK + nn + zq);
    #pragma unroll
    for (int u=0; u<8; ++u){
      int row = w*64 + u*8 + lrow;
      gl_lds16((const char*)(SFTb + (size_t)row*NTOK) + n0*2 + lsrc,
               BL + (w*64 + u*8)*128);
    }
    {
      float g20 = gs[zm];
      unsigned wd[4] = {zwc.x, zwc.y, zwc.z, zwc.w};
      union{ s16x8 v; u16 us[8]; } w0, w1;
      int sbase = n0 - nbeg + zq;
      #pragma unroll
      for (int col=0; col<16; ++col){
        float val = __expf(sfv[sbase+col] + g20 + DEC8(wd[col>>2], col&3));
        if (col < 8) w0.us[col] = f2bf(val); else w1.us[col-8] = f2bf(val);
      }
      *(s16x8*)(WtL + swz128(zm, zq*2)) = w0.v;
      *(s16x8*)(WtL + swz128(zm, zq*2+16)) = w1.v;
    }
    __syncthreads();
    #pragma unroll
    for (int kk=0; kk<2; ++kk){
      s16x8 a[4];
      #pragma unroll
      for (int mf=0;mf<4;++mf) a[mf] = *(const s16x8*)(WtL + swz128(mf*16+lc, kk*64 + g4*16));
      #pragma unroll
      for (int cf=0; cf<4; ++cf){
        s16x8 bb = *(const s16x8*)(BL + swz128(w*64+cf*16+lc, kk*64 + g4*16));
        #pragma unroll
        for (int mf=0; mf<4; ++mf)
          acc[mf][cf] = __builtin_amdgcn_mfma_f32_16x16x32_bf16(a[mf], bb, acc[mf][cf], 0,0,0);
      }
    }
    zwc = zwn;
  }
  float* FUb = FUF + (size_t)b*NTOK*CCH;
  #pragma unroll
  for (int mf=0; mf<4; ++mf)
    #pragma unroll
    for (int cf=0; cf<4; ++cf)
      #pragma unroll
      for (int r=0;r<4;++r){
        int m = m0 + mf*16 + g4*4 + r;
        int c = w*64 + cf*16 + lc;
        atomicAdd(&FUb[(size_t)m*CCH + c], acc[mf][cf][r]);
      }
}

// -------- out_feat = img + op_w @ fused + op_b (f32 out); also [b][n][c] bf16 copy --------
__global__ __launch_bounds__(256) void k_opgemm(const float* FUF, const float* opw, const float* opb,
    const float* img, float* dout, u16* OFN){
  int b=blockIdx.y, n0=blockIdx.x*64;
  __shared__ __align__(16) char Am[64*512];
  __shared__ __align__(16) char Bw[256*64];
  int tid=threadIdx.x, w=tid>>6, l=tid&63, g4=l>>4, lc=l&15;
  const float* FUb = FUF + (size_t)b*NTOK*CCH;
  for (int ch=tid; ch<64*32; ch+=256){
    int r=ch>>5, c8=(ch&31)*8;
    const float* fp = FUb + (size_t)(n0+r)*CCH + c8;
    float4 v0 = *(const float4*)fp;
    float4 v1 = *(const float4*)(fp+4);
    union { s16x8 v; u16 us[8]; } pk;
    pk.us[0]=f2bf(v0.x); pk.us[1]=f2bf(v0.y); pk.us[2]=f2bf(v0.z); pk.us[3]=f2bf(v0.w);
    pk.us[4]=f2bf(v1.x); pk.us[5]=f2bf(v1.y); pk.us[6]=f2bf(v1.z); pk.us[7]=f2bf(v1.w);
    *(s16x8*)(Am + swz512(r, c8*2)) = pk.v;
  }
  f32x4 acc[4][4];
  #pragma unroll
  for (int mf=0;mf<4;++mf)
    #pragma unroll
    for (int cf=0;cf<4;++cf) acc[mf][cf] = (f32x4){0.f,0.f,0.f,0.f};
  for (int ks=0; ks<8; ++ks){
    __syncthreads();
    {
      int o = tid;
      const float* wr = opw + (size_t)o*CCH + ks*32;
      #pragma unroll
      for (int u=0; u<4; ++u){
        float4 v0 = *(const float4*)(wr + u*8);
        float4 v1 = *(const float4*)(wr + u*8 + 4);
        union { s16x8 v; u16 us[8]; } pk;
        pk.us[0]=f2bf(v0.x); pk.us[1]=f2bf(v0.y); pk.us[2]=f2bf(v0.z); pk.us[3]=f2bf(v0.w);
        pk.us[4]=f2bf(v1.x); pk.us[5]=f2bf(v1.y); pk.us[6]=f2bf(v1.z); pk.us[7]=f2bf(v1.w);
        *(s16x8*)(Bw + swz64(o, u*16)) = pk.v;
      }
    }
    __syncthreads();
    #pragma unroll
    for (int mf=0; mf<4; ++mf){
      s16x8 a = *(const s16x8*)(Am + swz512(mf*16+lc, (ks*32+g4*8)*2));
      #pragma unroll
      for (int cf=0; cf<4; ++cf){
        int o = w*64+cf*16+lc;
        s16x8 bb = *(const s16x8*)(Bw + swz64(o, g4*16));
        acc[mf][cf] = __builtin_amdgcn_mfma_f32_16x16x32_bf16(a, bb, acc[mf][cf], 0,0,0);
      }
    }
  }
  #pragma unroll
  for (int mf=0; mf<4; ++mf){
    int nl = mf*16 + g4*4; int n = n0+nl;
    #pragma unroll
    for (int cf=0; cf<4; ++cf){
      int o = w*64+cf*16+lc;
      float ob = opb[o];
      const float* ip = img + ((size_t)b*CCH + o)*NTOK + n;
      float4 im = *(const float4*)ip;
      float o0 = acc[mf][cf][0]+ob+im.x;
      float o1 = acc[mf][cf][1]+ob+im.y;
      float o2 = acc[mf][cf][2]+ob+im.z;
      float o3 = acc[mf][cf][3]+ob+im.w;
      float4 st; st.x=o0; st.y=o1; st.z=o2; st.w=o3;
      *(float4*)(dout + ((size_t)b*CCH+o)*NTOK + n) = st;
      u16* ofp = OFN + ((size_t)b*NTOK + n)*CCH + o;
      ofp[0]=f2bf(o0); ofp[CCH]=f2bf(o1); ofp[2*CCH]=f2bf(o2); ofp[3*CCH]=f2bf(o3);
    }
  }
}

// -------- fused conv3x3 heads as LDS-staged implicit GEMM, pipelined --------
__global__ __launch_bounds__(256, 2) void k_conv2(const u16* OFN, const u16* W2P,
    const float* h1b, const float* v1b, u16* H1, u16* H2){
  int b = blockIdx.y, n0 = blockIdx.x*64;
  __shared__ __align__(16) char As[64*128];        // [row][64 K] bf16 swz128
  __shared__ __align__(16) char Ws[2][256*128];    // [o][64 K] bf16 swz128, double buffer
  int tid=threadIdx.x, w=tid>>6, l=tid&63, g4=l>>4, lc=l&15;
  int ar = tid>>2, aseg = (tid&3)*16;
  int arow = n0 + ar;
  int hr = arow/48, wc = arow - hr*48;
  const u16* Ob = OFN + (size_t)b*NTOK*CCH;
  int wrow = tid>>3;
  int wsrc = ((tid&7)*16) ^ ((wrow&7)<<4);
  const char* Wbase = (const char*)W2P;
  f32x4 acc[4][4];
  #pragma unroll
  for (int mf=0;mf<4;++mf)
    #pragma unroll
    for (int of=0;of<4;++of) acc[mf][of] = (f32x4){0.f,0.f,0.f,0.f};
  auto STAGEW = [&](int kc, int buf){
    const char* src = Wbase + (size_t)kc*32768;
    #pragma unroll
    for (int u=0; u<8; ++u)
      gl_lds16(src + (size_t)(u*32 + wrow)*128 + wsrc, Ws[buf] + u*4096 + w*1024);
  };
  auto LOADA = [&](int kc, s16x8& ra0, s16x8& ra1){
    int tap = kc>>2, cq = (kc&3)*64;
    int kh = tap/3;
    int dh = kh-1, dw = (tap-kh*3)-1;
    bool val = ((unsigned)(hr+dh) < 48u) && ((unsigned)(wc+dw) < 48u);
    ra0 = (s16x8){0,0,0,0,0,0,0,0}; ra1 = ra0;
    if (val){
      const u16* ap = Ob + (size_t)(arow + dh*48 + dw)*CCH + cq + aseg;
      ra0 = *(const s16x8*)ap;
      ra1 = *(const s16x8*)(ap+8);
    }
  };
  s16x8 a0, a1, na0, na1;
  STAGEW(0, 0);
  LOADA(0, a0, a1);
  for (int kc=0; kc<36; ++kc){
    int cur = kc & 1;
    __builtin_amdgcn_s_barrier();
    __builtin_amdgcn_sched_barrier(0);
    if (kc+1 < 36){
      STAGEW(kc+1, cur^1);
      LOADA(kc+1, na0, na1);
    }
    *(s16x8*)(As + swz128(ar, aseg*2))    = a0;
    *(s16x8*)(As + swz128(ar, aseg*2+16)) = a1;
    asm volatile("s_waitcnt lgkmcnt(0)" ::: "memory");
    __builtin_amdgcn_s_barrier();
    __builtin_amdgcn_sched_barrier(0);
    #pragma unroll
    for (int ks=0; ks<2; ++ks){
      s16x8 af[4];
      #pragma unroll
      for (int mf=0;mf<4;++mf) af[mf] = *(const s16x8*)(As + swz128(mf*16+lc, ks*64 + g4*16));
      #pragma unroll
      for (int of=0; of<4; ++of){
        s16x8 bf = *(const s16x8*)(Ws[cur] + swz128(w*64+of*16+lc, ks*64 + g4*16));
        #pragma unroll
        for (int mf=0; mf<4; ++mf)
          acc[mf][of] = __builtin_amdgcn_mfma_f32_16x16x32_bf16(af[mf], bf, acc[mf][of], 0,0,0);
      }
    }
    a0 = na0; a1 = na1;
  }
  #pragma unroll
  for (int of=0; of<4; ++of){
    int o = w*64 + of*16 + lc;
    int head = o>>7, oc = o&127;
    float bias = (head? v1b : h1b)[oc];
    u16* Hh = head? H2 : H1;
    #pragma unroll
    for (int mf=0; mf<4; ++mf){
      #pragma unroll
      for (int r=0;r<4;++r){
        int n = n0 + mf*16 + g4*4 + r;
        Hh[((size_t)b*NTOK+n)*128 + oc] = f2bf(acc[mf][of][r] + bias);
      }
    }
  }
}

// -------- BN batch stats (two-stage, deterministic) --------
__global__ __launch_bounds__(128) void k_stats(const u16* H1, const u16* H2, float* PART){
  int head=blockIdx.y, blk=blockIdx.x, t=threadIdx.x;
  const u16* Hh = head? H2:H1;
  float s=0.f, ss=0.f;
  size_t r0 = (size_t)blk*288;
  for (int r=0;r<288;++r){
    float v = bf2f(Hh[(r0+r)*128 + t]);
    s += v; ss = fmaf(v,v,ss);
  }
  PART[((head*64+blk)*128+t)*2]   = s;
  PART[((head*64+blk)*128+t)*2+1] = ss;
}

__global__ __launch_bounds__(128) void k_statr(const float* PART, const float* hbg, const float* hbb,
    const float* vbg, const float* vbb, float* BNS){
  int head=blockIdx.x, t=threadIdx.x;
  float s=0.f, ss=0.f;
  for (int blk=0;blk<64;++blk){
    s  += PART[((head*64+blk)*128+t)*2];
    ss += PART[((head*64+blk)*128+t)*2+1];
  }
  float mean = s*(1.f/18432.f);
  float var = ss*(1.f/18432.f) - mean*mean;
  var = fmaxf(var, 0.f);
  const float* g  = head? vbg:hbg;
  const float* be = head? vbb:hbb;
  float sc = g[t]/sqrtf(var+1e-5f);
  BNS[(head*128+t)*2]   = sc;
  BNS[(head*128+t)*2+1] = be[t] - mean*sc;
}

// -------- BN-normalize + relu + conv1x1(128->2), f32 out --------
__global__ __launch_bounds__(128) void k_fin(const u16* H1, const u16* H2, const float* BNS,
    const float* h2w, const float* h2b, const float* v2w, const float* v2b, float* dout){
  int head = blockIdx.z, b = blockIdx.y, n0 = blockIdx.x*128, t=threadIdx.x;
  const u16* Hh = head? H2:H1;
  const float* w2 = head? v2w:h2w;
  const float* b2 = head? v2b:h2b;
  __shared__ u16 tile[128][130];
  __shared__ float sc[128], bi[128], wa[128], wb[128];
  sc[t]=BNS[(head*128+t)*2]; bi[t]=BNS[(head*128+t)*2+1];
  wa[t]=w2[t]; wb[t]=w2[128+t];
  for (int r=0;r<128;++r) tile[r][t] = Hh[((size_t)b*NTOK+n0+r)*128 + t];
  __syncthreads();
  float a0=b2[0], a1=b2[1];
  for (int ch=0; ch<128; ++ch){
    float v = fmaf(bf2f(tile[t][ch]), sc[ch], bi[ch]);
    v = fmaxf(v, 0.f);
    a0 = fmaf(wa[ch], v, a0);
    a1 = fmaf(wb[ch], v, a1);
  }
  size_t base = (size_t)8*256*2304 + (size_t)head*36864 + (size_t)b*2*2304 + n0 + t;
  dout[base]        = a0;
  dout[base+2304]   = a1;
}

extern "C" void kernel_launch(void* const* d_in, const int* in_sizes, int n_in,
                              void* d_out, int out_size, void* d_ws, size_t ws_size,
                              hipStream_t stream){
  (void)out_size;
  long off[31]; long tot=0;
  int ni = n_in < 31 ? n_in : 31;
  for (int i=0;i<ni;++i){ off[i]=tot; tot += ((long)in_sizes[i]+63)&~63L; }  // 64-elem pad => 16B-aligned float4
  char* ws = (char*)d_ws;
  size_t pos = 0;
  auto alloc = [&](size_t bytes)->char*{
    char* p = ws+pos; pos = (pos + bytes + 255) & ~(size_t)255; return p; };
  int*   FLAG = (int*)alloc(256);
  float* TXTN = (float*)alloc(8*256*4);
  float* AVEC = (float*)alloc(8*256*4);
  float* COS  = (float*)alloc(8*2304*4);
  float* LOGP = (float*)alloc(8*2304*4);
  float* LOGQ = (float*)alloc(8*2304*4);
  float* FV   = (float*)alloc(8*2304*4);
  float* GV   = (float*)alloc(8*2304*4);
  u16*   PJ   = (u16*)alloc(2304*2);
  float* SPT  = (float*)alloc(9025*4);
  float* PQS  = (float*)alloc(8*4*4);
  float* PART = (float*)alloc(2*64*128*2*4);
  float* BNS  = (float*)alloc(2*128*2*4);
  float* PZ   = (float*)alloc((size_t)8*2304*9*4);
  u16* W2P = (u16*)alloc((size_t)36*256*64*2);
  u16* SF  = (u16*)alloc((size_t)8*2304*256*2);
  u16* SN  = (u16*)alloc((size_t)8*2304*256*2);
  u16* SFT = (u16*)alloc((size_t)8*2304*256*2);
  float* FUF = (float*)alloc((size_t)8*2304*256*4);   // f32 accumulator (atomic, 2-way deterministic)
  u16* OFN = (u16*)alloc((size_t)8*2304*256*2);
  u16* H1  = (u16*)alloc((size_t)8*2304*128*2);
  u16* H2  = (u16*)alloc((size_t)8*2304*128*2);
  float* canon = (float*)alloc((size_t)tot*4);
  size_t zslice = (size_t)NTOK*NTOK;           // fp8: 1 byte/elem
  int zsl = (pos + 8*zslice + 256 <= ws_size) ? 8 : 1;
  u8* Z = (u8*)alloc((size_t)zsl*zslice);

  k_detect<<<1,64,0,stream>>>((const u16*)d_in[1], FLAG);
  CanonArgs ca;
  for (int i=0;i<ni;++i){ ca.src[i]=d_in[i]; ca.n[i]=in_sizes[i]; ca.off[i]=(int)off[i]; }
  k_canon<<<dim3(512,(unsigned)ni),256,0,stream>>>(ca, canon, FLAG, ni);
  k_zero<<<4608,256,0,stream>>>(FUF, 8*2304*256/4);

  const float* c_img = canon+off[0];
  const float* c_txt = canon+off[1];
  const float* c_den = canon+off[2];
  const float* c_tpw = canon+off[3];
  const float* c_tpb = canon+off[4];
  const float* c_wv  = canon+off[9];
  const float* c_bv  = canon+off[10];
  const float* c_wo  = canon+off[11];
  const float* c_bo  = canon+off[12];
  const float* c_lng = canon+off[13];
  const float* c_lnb = canon+off[14];
  const float* c_opw = canon+off[15];
  const float* c_opb = canon+off[16];
  const float* c_h1w = canon+off[17];
  const float* c_h1b = canon+off[18];
  const float* c_hbg = canon+off[19];
  const float* c_hbb = canon+off[20];
  const float* c_h2w = canon+off[21];
  const float* c_h2b = canon+off[22];
  const float* c_v1w = canon+off[23];
  const float* c_v1b = canon+off[24];
  const float* c_vbg = canon+off[25];
  const float* c_vbb = canon+off[26];
  const float* c_v2w = canon+off[27];
  const float* c_v2b = canon+off[28];
  const float* c_tmp = canon+off[29];
  const float* c_sw  = canon+off[30];

  k_txt<<<8,256,0,stream>>>(c_txt, c_tpw, c_tpb, c_wv, c_bv, c_wo, c_bo, TXTN, AVEC);
  k_lnfuse<<<dim3(72,8),256,0,stream>>>(c_img, AVEC, c_lng, c_lnb, TXTN, SF, SN, COS);
  k_pqred<<<8,256,0,stream>>>(COS, c_den, c_tmp, PQS);
  k_pqelem<<<80,256,0,stream>>>(COS, c_den, c_tmp, c_sw, PQS, LOGP, LOGQ, GV, PJ, SPT);
  k_packw<<<2304,256,0,stream>>>(c_h1w, c_v1w, W2P);
  k_trans<<<dim3(36,4,8),256,0,stream>>>(SF, SFT);

  if (zsl == 8){
    k_cost<<<dim3(36,9,8),256,0,stream>>>(SN, PJ, SPT, Z, PZ, 0);
    k_sinkred<<<72,256,0,stream>>>(PZ, LOGP, FV, 0, 8);        // fused first f-pass
    for (int it=0; it<3; ++it){
      if (it>0) k_sinkZ<<<dim3(72,8),256,0,stream>>>(Z, GV, LOGP, FV, 0);
      k_sinkZ<<<dim3(72,8),256,0,stream>>>(Z, FV, LOGQ, GV, 0);
    }
    k_applyT<<<dim3(36,NSPL,8),256,0,stream>>>(Z, SFT, FV, GV, FUF, 0);
  } else {
    for (int bi=0; bi<8; ++bi){
      k_cost<<<dim3(36,9,1),256,0,stream>>>(SN, PJ, SPT, Z, PZ, bi);
      k_sinkred<<<9,256,0,stream>>>(PZ, LOGP, FV, bi, 1);
      for (int it=0; it<3; ++it){
        if (it>0) k_sinkZ<<<dim3(72,1),256,0,stream>>>(Z, GV, LOGP, FV, bi);
        k_sinkZ<<<dim3(72,1),256,0,stream>>>(Z, FV, LOGQ, GV, bi);
      }
      k_applyT<<<dim3(36,NSPL,1),256,0,stream>>>(Z, SFT, FV, GV, FUF, bi);
    }
  }

  k_opgemm<<<dim3(36,8),256,0,stream>>>(FUF, c_opw, c_opb, c_img, (float*)d_out, OFN);
  k_conv2<<<dim3(36,8),256,0,stream>>>(OFN, W2P, c_h1b, c_v1b, H1, H2);
  k_stats<<<dim3(64,2),128,0,stream>>>(H1, H2, PART);
  k_statr<<<2,128,0,stream>>>(PART, c_hbg, c_hbb, c_vbg, c_vbb, BNS);
  k_fin<<<dim3(18,8,2),128,0,stream>>>(H1, H2, BNS, c_h2w, c_h2b, c_v2w, c_v2b, (float*)d_out);
}